// Round 8
// baseline (632.288 us; speedup 1.0000x reference)
//
#include <hip/hip_runtime.h>
#include <hip/hip_bf16.h>
#include <cstdint>

// Conformer block, MI355X gfx950. f32 inputs, f32 output, bf16 MFMA internals.
// B=8 N=1024 D=512 H=8 DH=64 FF=2048 CI=1024 K=31 MPE=512.
// Round 17: gemm BK=64 (half the barrier/vmcnt drains), attn swapped-operand
// T-compute (18 packed b64 T-stores vs 72 scalar b16), dwconv vectorized
// staging. Flash softmax + batched prep retained from R16.

using bf16_t = __hip_bfloat16;
typedef __bf16 bf16x8 __attribute__((ext_vector_type(8)));
typedef float floatx4 __attribute__((ext_vector_type(4)));

struct alignas(16) hbf8 { bf16_t h[8]; };
struct alignas(8)  hbf4 { bf16_t h[4]; };

__device__ __forceinline__ float  b2f(bf16_t h) { return __bfloat162float(h); }
__device__ __forceinline__ bf16_t f2b(float f)  { return __float2bfloat16(f); }
__device__ __forceinline__ float  sig_(float x) { return 1.f / (1.f + __expf(-x)); }

// pack 2 f32 -> 2 bf16 in one u32 (low 16 = a, high = b); pure C (R4-verified)
__device__ __forceinline__ unsigned pkbf(float a, float b) {
  bf16_t ha = f2b(a), hb = f2b(b);
  unsigned short ua, ub;
  __builtin_memcpy(&ua, &ha, 2);
  __builtin_memcpy(&ub, &hb, 2);
  return (unsigned)ua | ((unsigned)ub << 16);
}

// async global->LDS, 16B/lane; LDS dest must be wave-uniform base + lane*16 (m97 pattern)
__device__ __forceinline__ void async16(const void* g, void* l) {
  __builtin_amdgcn_global_load_lds(
      (const __attribute__((address_space(1))) unsigned int*)(uintptr_t)g,
      (__attribute__((address_space(3))) unsigned int*)(uintptr_t)l, 16, 0, 0);
}

// ---------------------------------------------------------------- GEMM (MFMA)
// C[M,N] = A[M,K] @ Bt[N,K]^T   (bf16 operands, k-contiguous, f32 accum)
// BK = 64: two 16x16x32 k-halves per tile stage; half the barriers of BK=32.
// EPI 0: C_bf16 = alpha*acc + bias
// EPI 1: C_bf16 = swish(acc + bias)
// EPI 2: resid_f32 = (srcf ? srcf[i] : resid[i]) + beta*(acc+bias)
// EPI 4: GLU: bias idx (j>>1)+(j&1)*1024; even-j lanes write
//        C[i][j>>1] = v * sig(partner v) (cw1t stored column-interleaved)
struct GemmArgs {
  const bf16_t* A; const bf16_t* Bt; const float* bias; const float* srcf;
  bf16_t* C; float* resid;
  int K, lda, ldb, ldc;
  long sAb, sAh, sBb, sBh, sCb, sCh;
  float alpha, beta;
};

template <int BM, int BN, int WR, int WC, int EPI>
__global__ __launch_bounds__(256) void gemm_bt(GemmArgs g) {
  constexpr int FM = BM / (WR * 16);
  constexpr int FN = BN / (WC * 16);
  constexpr int IA = BM / 32;            // chunks of 16B per thread for A (BK=64)
  constexpr int IB = BN / 32;
  __shared__ __align__(16) bf16_t As[BM * 64];
  __shared__ __align__(16) bf16_t Bs[BN * 64];
  const int tid = threadIdx.x;
  const int lane = tid & 63, w = tid >> 6;
  // XCD-chunked bijective remap (nwg % 8 == 0 for all our launches)
  int bx = blockIdx.x, by = blockIdx.y;
  {
    const int gx = gridDim.x;
    const int nwg = gx * gridDim.y;
    if ((nwg & 7) == 0 && gridDim.z == 1) {
      int lin = by * gx + bx;
      int lid = (lin & 7) * (nwg >> 3) + (lin >> 3);
      bx = lid % gx; by = lid / gx;
    }
  }
  const int bm0 = by * BM, bn0 = bx * BN;
  const int zb = blockIdx.z >> 3, zh = blockIdx.z & 7;
  const bf16_t* Ab = g.A + (long)zb * g.sAb + (long)zh * g.sAh;
  const bf16_t* Bb = g.Bt + (long)zb * g.sBb + (long)zh * g.sBh;
  const int wm0 = (w / WC) * (FM * 16);
  const int wn0 = (w % WC) * (FN * 16);
  const int lrow = lane & 15, lq = lane >> 4;

  floatx4 acc[FM][FN] = {};

  for (int k0 = 0; k0 < g.K; k0 += 64) {
#pragma unroll
    for (int i = 0; i < IA; ++i) {
      int c = i * 256 + tid;
      int m = c >> 3, kk = (c & 7) * 8;
      async16(Ab + (long)(bm0 + m) * g.lda + (k0 + kk), (char*)As + c * 16);
    }
#pragma unroll
    for (int i = 0; i < IB; ++i) {
      int c = i * 256 + tid;
      int n = bn0 + (c >> 3), kk = (c & 7) * 8;
      async16(Bb + (long)n * g.ldb + (k0 + kk), (char*)Bs + c * 16);
    }
    __syncthreads();   // drains vmcnt before s_barrier (compiler-inserted)
#pragma unroll
    for (int ks = 0; ks < 2; ++ks) {
      bf16x8 af[FM], bfr[FN];
#pragma unroll
      for (int fm = 0; fm < FM; ++fm)
        af[fm] = *(const bf16x8*)(As + (wm0 + fm * 16 + lrow) * 64 + ks * 32 + lq * 8);
#pragma unroll
      for (int fn = 0; fn < FN; ++fn)
        bfr[fn] = *(const bf16x8*)(Bs + (wn0 + fn * 16 + lrow) * 64 + ks * 32 + lq * 8);
#pragma unroll
      for (int fm = 0; fm < FM; ++fm)
#pragma unroll
        for (int fn = 0; fn < FN; ++fn)
          acc[fm][fn] = __builtin_amdgcn_mfma_f32_16x16x32_bf16(af[fm], bfr[fn], acc[fm][fn], 0, 0, 0);
    }
    __syncthreads();
  }

  const int bi = bm0 + wm0 + lq * 4;    // + fm*16 + r
  const int bj = bn0 + wn0 + lrow;      // + fn*16
  if constexpr (EPI == 2) {
    float* R = g.resid;
    const float* S = g.srcf;
#pragma unroll
    for (int fm = 0; fm < FM; ++fm)
#pragma unroll
      for (int fn = 0; fn < FN; ++fn) {
        int j = bj + fn * 16;
        float bv = g.bias ? g.bias[j] : 0.f;
#pragma unroll
        for (int r = 0; r < 4; ++r) {
          long i = bi + fm * 16 + r;
          float base = S ? S[i * g.ldc + j] : R[i * g.ldc + j];
          R[i * g.ldc + j] = base + g.beta * (acc[fm][fn][r] + bv);
        }
      }
  } else if constexpr (EPI == 4) {
    bf16_t* C = g.C;
#pragma unroll
    for (int fm = 0; fm < FM; ++fm)
#pragma unroll
      for (int fn = 0; fn < FN; ++fn) {
        int j = bj + fn * 16;
        float bv = g.bias[(j >> 1) + (j & 1) * 1024];
#pragma unroll
        for (int r = 0; r < 4; ++r) {
          int i = bi + fm * 16 + r;
          float v = acc[fm][fn][r] + bv;
          float gp = __shfl_xor(v, 1);
          if ((j & 1) == 0)
            C[(long)i * g.ldc + (j >> 1)] = f2b(v * sig_(gp));
        }
      }
  } else {
    bf16_t* C = g.C + (long)zb * g.sCb + (long)zh * g.sCh;
#pragma unroll
    for (int fm = 0; fm < FM; ++fm)
#pragma unroll
      for (int fn = 0; fn < FN; ++fn) {
        int j = bj + fn * 16;
        float bv = g.bias ? g.bias[j] : 0.f;
#pragma unroll
        for (int r = 0; r < 4; ++r) {
          int i = bi + fm * 16 + r;
          float v = acc[fm][fn][r];
          if constexpr (EPI == 0) v = g.alpha * v + bv;
          if constexpr (EPI == 1) { v += bv; v = v * sig_(v); }
          C[(long)i * g.ldc + j] = f2b(v);
        }
      }
  }
}

// ---------------------------------------------------------------- fused attention
// One block = one (z = b*8+h, 32-row i-tile). 512 threads = 8 waves.
// Wave w owns j-slab [w*128, w*128+128).
// Phase 0: T[i][u] via SWAPPED mfma(rel, q): lane holds 4 consecutive u for
//          row i=lane&15 -> packed b64 stores (18 vs 72 scalar).
// Phase 1: S = Q K^T (regs, K prefetched) + bias gathered from T.
// Phase 2: wave-local softmax (flash rescale deferred to K-reduce).
// Phase 3: unnormalized P -> LDS (XOR-swizzled, aliases T), PV with VT
//          prefetched, K-split partials rescaled+normalized in the reduce.
// QKV: bf16 [(b*1024+n)*1536 + {q:0|k:512|v:1024} + h*64 + d] (q pre-scaled 1/8)
// VT: bf16 [(b*8+h)*65536 + d*1024 + j]
// RELP: bf16 [1152][64] (rows >=1025 zero)
// O: bf16 [(b*1024+i)*512 + h*64 + d]
__global__ __launch_bounds__(512, 4) void attn_kernel(
    const bf16_t* __restrict__ QKV, const bf16_t* __restrict__ VT,
    const bf16_t* __restrict__ RELP, bf16_t* __restrict__ O) {
  constexpr int LDT = 1028;                         // 2056 B row -> 2-bank rotate
  __shared__ __align__(16) bf16_t Tls[32 * LDT];    // 65792 B; aliased: T -> P -> partials
  __shared__ float scr[576];  // [0,288) m_w (stride 9), [288,576) s_w

  const int tid = threadIdx.x;
  const int w = tid >> 6, lane = tid & 63;
  const int lrow = lane & 15, lq = lane >> 4;
  // XCD-chunked remap: 2048 blocks; each XCD gets all 32 i-tiles of 8 z's
  const int lin = blockIdx.y * gridDim.x + blockIdx.x;   // gridDim.x = 32
  const int lid = (lin & 7) * 256 + (lin >> 3);
  const int z = lid >> 5;
  const int i0 = (lid & 31) * 32;
  const int b = z >> 3, zh = z & 7;
  const int j0w = w * 128;

  const bf16_t* Qb  = QKV + ((long)(b * 1024 + i0)) * 1536 + zh * 64;
  const bf16_t* Kb  = QKV + ((long)b * 1024) * 1536 + 512 + zh * 64;
  const bf16_t* VTb = VT + ((long)(b * 8 + zh)) * 65536;

  // Q fragments: af[fm][ks] covers rows fm*16..+15 (lane lrow), k-half ks.
  // Same register layout serves as A-operand (phase 1) and B-operand (phase 0).
  bf16x8 af[2][2];
#pragma unroll
  for (int fm = 0; fm < 2; ++fm)
#pragma unroll
    for (int ks = 0; ks < 2; ++ks)
      af[fm][ks] = *(const bf16x8*)(Qb + (long)(fm * 16 + lrow) * 1536 + ks * 32 + lq * 8);

  // ---- phase 0: T[i][u] via swapped tiles = mfma(rel, q); packed b64 stores ----
  {
    const int u0w = w * 144;
    bf16x8 rf[18];
#pragma unroll
    for (int fnT = 0; fnT < 9; ++fnT) {
      const int u0 = u0w + fnT * 16;
      if (u0 <= 1024) {
        rf[2 * fnT]     = *(const bf16x8*)(RELP + (long)(u0 + lrow) * 64 + lq * 8);
        rf[2 * fnT + 1] = *(const bf16x8*)(RELP + (long)(u0 + lrow) * 64 + 32 + lq * 8);
      }
    }
#pragma unroll
    for (int fnT = 0; fnT < 9; ++fnT) {
      const int u0 = u0w + fnT * 16;
      if (u0 <= 1024) {
#pragma unroll
        for (int fm = 0; fm < 2; ++fm) {
          floatx4 t4 = {};
          t4 = __builtin_amdgcn_mfma_f32_16x16x32_bf16(rf[2 * fnT],     af[fm][0], t4, 0, 0, 0);
          t4 = __builtin_amdgcn_mfma_f32_16x16x32_bf16(rf[2 * fnT + 1], af[fm][1], t4, 0, 0, 0);
          // lane holds T[i = fm*16+lrow][u = u0+lq*4+r], r=0..3 (consecutive u)
          if (u0 + lq * 4 + 4 <= LDT) {
            uint2 v; v.x = pkbf(t4[0], t4[1]); v.y = pkbf(t4[2], t4[3]);
            *(uint2*)(Tls + (long)(fm * 16 + lrow) * LDT + u0 + lq * 4) = v;
          }
        }
      }
    }
  }

  // K fragment prefetch (issued before the barrier; consumed after)
  bf16x8 kfA[8], kfB[8];
#pragma unroll
  for (int x = 0; x < 8; ++x)
    kfA[x] = *(const bf16x8*)(Kb + (long)(j0w + (x >> 1) * 16 + lrow) * 1536 + (x & 1) * 32 + lq * 8);
#pragma unroll
  for (int x = 0; x < 8; ++x)
    kfB[x] = *(const bf16x8*)(Kb + (long)(j0w + (4 + (x >> 1)) * 16 + lrow) * 1536 + (x & 1) * 32 + lq * 8);
  __syncthreads();   // barrier 1: T visible to all waves

  // ---- phase 1: S = Q K^T (f32 in regs) + bias from T ----
  floatx4 sacc[2][8] = {};
#pragma unroll
  for (int fn = 0; fn < 4; ++fn) {
    sacc[0][fn] = __builtin_amdgcn_mfma_f32_16x16x32_bf16(af[0][0], kfA[2 * fn],     sacc[0][fn], 0, 0, 0);
    sacc[0][fn] = __builtin_amdgcn_mfma_f32_16x16x32_bf16(af[0][1], kfA[2 * fn + 1], sacc[0][fn], 0, 0, 0);
    sacc[1][fn] = __builtin_amdgcn_mfma_f32_16x16x32_bf16(af[1][0], kfA[2 * fn],     sacc[1][fn], 0, 0, 0);
    sacc[1][fn] = __builtin_amdgcn_mfma_f32_16x16x32_bf16(af[1][1], kfA[2 * fn + 1], sacc[1][fn], 0, 0, 0);
  }
#pragma unroll
  for (int fn = 4; fn < 8; ++fn) {
    sacc[0][fn] = __builtin_amdgcn_mfma_f32_16x16x32_bf16(af[0][0], kfB[2 * (fn - 4)],     sacc[0][fn], 0, 0, 0);
    sacc[0][fn] = __builtin_amdgcn_mfma_f32_16x16x32_bf16(af[0][1], kfB[2 * (fn - 4) + 1], sacc[0][fn], 0, 0, 0);
    sacc[1][fn] = __builtin_amdgcn_mfma_f32_16x16x32_bf16(af[1][0], kfB[2 * (fn - 4)],     sacc[1][fn], 0, 0, 0);
    sacc[1][fn] = __builtin_amdgcn_mfma_f32_16x16x32_bf16(af[1][1], kfB[2 * (fn - 4) + 1], sacc[1][fn], 0, 0, 0);
  }

  // rel-pos bias gather from LDS: bias[i][j] = T[i_local][clip(i-j,+-512)+512]
#pragma unroll
  for (int fm = 0; fm < 2; ++fm)
#pragma unroll
    for (int r = 0; r < 4; ++r) {
      const int il = fm * 16 + lq * 4 + r;
      const bf16_t* trow = Tls + il * LDT + 512;
      const int tb = i0 + il - j0w - lrow;
#pragma unroll
      for (int fn = 0; fn < 8; ++fn) {
        int t = tb - fn * 16;
        t = t < -512 ? -512 : (t > 512 ? 512 : t);
        sacc[fm][fn][r] += b2f(trow[t]);
      }
    }

  // ---- phase 2: wave-local softmax (flash rescale deferred to reduce) ----
  float rmax[2][4];
#pragma unroll
  for (int fm = 0; fm < 2; ++fm)
#pragma unroll
    for (int r = 0; r < 4; ++r) {
      float m = sacc[fm][0][r];
#pragma unroll
      for (int fn = 1; fn < 8; ++fn) m = fmaxf(m, sacc[fm][fn][r]);
      rmax[fm][r] = m;
    }
#pragma unroll
  for (int off = 1; off < 16; off <<= 1)   // reduce across the 16 j-lanes (lrow)
#pragma unroll
    for (int fm = 0; fm < 2; ++fm)
#pragma unroll
      for (int r = 0; r < 4; ++r)
        rmax[fm][r] = fmaxf(rmax[fm][r], __shfl_xor(rmax[fm][r], off));
  if (lrow == 0)
#pragma unroll
    for (int fm = 0; fm < 2; ++fm)
#pragma unroll
      for (int r = 0; r < 4; ++r)
        scr[(fm * 16 + lq * 4 + r) * 9 + w] = rmax[fm][r];

  float rsum[2][4];
#pragma unroll
  for (int fm = 0; fm < 2; ++fm)
#pragma unroll
    for (int r = 0; r < 4; ++r) {
      float s = 0.f;
#pragma unroll
      for (int fn = 0; fn < 8; ++fn) {
        float e = __expf(sacc[fm][fn][r] - rmax[fm][r]);
        sacc[fm][fn][r] = e;
        s += e;
      }
      rsum[fm][r] = s;
    }
#pragma unroll
  for (int off = 1; off < 16; off <<= 1)
#pragma unroll
    for (int fm = 0; fm < 2; ++fm)
#pragma unroll
      for (int r = 0; r < 4; ++r)
        rsum[fm][r] += __shfl_xor(rsum[fm][r], off);
  if (lrow == 0)
#pragma unroll
    for (int fm = 0; fm < 2; ++fm)
#pragma unroll
      for (int r = 0; r < 4; ++r)
        scr[288 + (fm * 16 + lq * 4 + r) * 9 + w] = rsum[fm][r];

  // VT prefetch, first half (ks 0,1)
  bf16x8 vfA[8];
#pragma unroll
  for (int x = 0; x < 8; ++x)   // x = ks*4 + fd, ks in {0,1}
    vfA[x] = *(const bf16x8*)(VTb + (long)((x & 3) * 16 + lrow) * 1024 + j0w + (x >> 2) * 32 + lq * 8);

  __syncthreads();   // barrier 2: all T gathers done -> safe to alias P over T

  // ---- phase 3a: unnormalized P -> LDS (XOR swizzle ^((i&7)<<4); wave-local) ----
#pragma unroll
  for (int fm = 0; fm < 2; ++fm)
#pragma unroll
    for (int fn = 0; fn < 8; ++fn)
#pragma unroll
      for (int r = 0; r < 4; ++r) {
        const int i = fm * 16 + lq * 4 + r;
        const int j = j0w + fn * 16 + lrow;
        const unsigned boff = (unsigned)(i * 2048 + j * 2) ^ ((unsigned)(i & 7) << 4);
        *(bf16_t*)((char*)Tls + boff) = f2b(sacc[fm][fn][r]);
      }
  // no barrier needed: each wave reads back only its own slab

  // VT prefetch, second half (ks 2,3)
  bf16x8 vfB[8];
#pragma unroll
  for (int x = 0; x < 8; ++x)   // x = ks*4 + fd, ks in {2,3}
    vfB[x] = *(const bf16x8*)(VTb + (long)((x & 3) * 16 + lrow) * 1024 + j0w + 64 + (x >> 2) * 32 + lq * 8);

  // ---- phase 3b: O partials = P_slab @ V_slab ----
  floatx4 oacc[2][4] = {};
#pragma unroll
  for (int ks = 0; ks < 4; ++ks) {
    const int j = j0w + ks * 32;
    bf16x8 ap[2];
#pragma unroll
    for (int fm = 0; fm < 2; ++fm) {
      const int i = fm * 16 + lrow;
      const unsigned boff = (unsigned)(i * 2048 + (j + lq * 8) * 2) ^ ((unsigned)(i & 7) << 4);
      ap[fm] = *(const bf16x8*)((char*)Tls + boff);
    }
#pragma unroll
    for (int fd = 0; fd < 4; ++fd) {
      bf16x8 bv = (ks < 2) ? vfA[(ks << 2) | fd] : vfB[((ks - 2) << 2) | fd];
      oacc[0][fd] = __builtin_amdgcn_mfma_f32_16x16x32_bf16(ap[0], bv, oacc[0][fd], 0, 0, 0);
      oacc[1][fd] = __builtin_amdgcn_mfma_f32_16x16x32_bf16(ap[1], bv, oacc[1][fd], 0, 0, 0);
    }
  }
  __syncthreads();   // barrier 3: all PV reads of P done -> overwrite with partials

  // partials: per-wave f32 [i][64] at float offset w*2048 (re-aliases LDS)
  {
    float* part = (float*)Tls + w * 2048;
#pragma unroll
    for (int fm = 0; fm < 2; ++fm)
#pragma unroll
      for (int fd = 0; fd < 4; ++fd)
#pragma unroll
        for (int r = 0; r < 4; ++r)
          part[(fm * 16 + lq * 4 + r) * 64 + fd * 16 + lrow] = oacc[fm][fd][r];
  }
  __syncthreads();   // barrier 4

  // K-reduce 8 partials with flash rescale + normalization, write O
  {
    const int i = tid >> 4;
    const int d0 = (tid & 15) * 4;
    float mw[8], sw[8];
#pragma unroll
    for (int ww = 0; ww < 8; ++ww) {
      mw[ww] = scr[i * 9 + ww];
      sw[ww] = scr[288 + i * 9 + ww];
    }
    float M = mw[0];
#pragma unroll
    for (int ww = 1; ww < 8; ++ww) M = fmaxf(M, mw[ww]);
    float fac[8]; float tot = 0.f;
#pragma unroll
    for (int ww = 0; ww < 8; ++ww) { fac[ww] = __expf(mw[ww] - M); tot += sw[ww] * fac[ww]; }
    const float inv = 1.f / tot;
    floatx4 s = {};
#pragma unroll
    for (int ww = 0; ww < 8; ++ww) {
      floatx4 p = *(const floatx4*)((const float*)Tls + ww * 2048 + i * 64 + d0);
      s += p * fac[ww];
    }
    hbf4 o4;
#pragma unroll
    for (int m = 0; m < 4; ++m) o4.h[m] = f2b(s[m] * inv);
    *(hbf4*)(O + (long)(b * 1024 + i0 + i) * 512 + zh * 64 + d0) = o4;
  }
}

// ---------------------------------------------------------------- glue kernels
__global__ __launch_bounds__(256) void diag_kernel(float* __restrict__ out, long n, float v) {
  long i = (long)blockIdx.x * 256 + threadIdx.x;
  if (i < n) out[i] = v;
}

// batched weight prep: 9 transposes (f32->bf16, optional scale / GLU perm) + relpad
struct PrepJobs {
  const float* src[10];
  bf16_t*      dst[10];
  int R[10], C[10], gx[10], start[10];
  float scale[10];
  int   mode[10];   // 0 transpose, 1 transpose+GLU col-interleave, 2 relpad
  int   njobs;
};

__global__ __launch_bounds__(256) void prep_kernel(PrepJobs P) {
  __shared__ float t[32][33];
  const int bid = blockIdx.x;
  int j = 0;
  while (j + 1 < P.njobs && bid >= P.start[j + 1]) ++j;
  const int tile = bid - P.start[j];
  const int tid = threadIdx.x;
  if (P.mode[j] == 2) {   // relpad: [1025,64] f32 -> [1152,64] bf16 (zero tail)
    int i = tile * 256 + tid;
    if (i < 73728) {
      int r = i >> 6, c = i & 63;
      P.dst[j][i] = (r < 1025) ? f2b(P.src[j][r * 64 + c]) : f2b(0.f);
    }
    return;
  }
  const int gx = P.gx[j];
  const int c0 = (tile % gx) * 32, r0 = (tile / gx) * 32;
  const int C = P.C[j], R = P.R[j];
  const float scale = P.scale[j];
  const int tx = tid & 31, ty = tid >> 5;
#pragma unroll
  for (int i = 0; i < 4; ++i)
    t[ty + i * 8][tx] = P.src[j][(long)(r0 + ty + i * 8) * C + c0 + tx];
  __syncthreads();
#pragma unroll
  for (int i = 0; i < 4; ++i) {
    int c = c0 + ty + i * 8;
    int row = (P.mode[j] == 1) ? ((c < 1024) ? 2 * c : 2 * (c - 1024) + 1) : c;
    P.dst[j][(long)row * R + r0 + tx] = f2b(t[tx][ty + i * 8] * scale);
  }
}

template <bool F32OUT>
__global__ __launch_bounds__(256) void ln_kernel(const float* __restrict__ X, const float* __restrict__ gam,
                                                 const float* __restrict__ bet, void* __restrict__ outv) {
  int row = blockIdx.x, tid = threadIdx.x;
  const float* x = X + (long)row * 512;
  float a = x[tid], b = x[tid + 256];
  float s = a + b, q = a * a + b * b;
  for (int off = 32; off; off >>= 1) { s += __shfl_down(s, off); q += __shfl_down(q, off); }
  __shared__ float red[8];
  int w = tid >> 6;
  if ((tid & 63) == 0) { red[w] = s; red[w + 4] = q; }
  __syncthreads();
  float ts = red[0] + red[1] + red[2] + red[3];
  float tq = red[4] + red[5] + red[6] + red[7];
  float mean = ts * (1.f / 512.f);
  float var = tq * (1.f / 512.f) - mean * mean;
  float rs = rsqrtf(var + 1e-5f);
  float o0 = (a - mean) * rs * gam[tid]       + bet[tid];
  float o1 = (b - mean) * rs * gam[tid + 256] + bet[tid + 256];
  if constexpr (F32OUT) {
    float* out = (float*)outv;
    out[(long)row * 512 + tid]       = o0;
    out[(long)row * 512 + tid + 256] = o1;
  } else {
    bf16_t* out = (bf16_t*)outv;
    out[(long)row * 512 + tid]       = f2b(o0);
    out[(long)row * 512 + tid + 256] = f2b(o1);
  }
}

// VT[z=b*8+h][d][j] = QKV[(b*1024+j)*1536 + 1024 + h*64 + d]
__global__ __launch_bounds__(256) void vt_kernel(const bf16_t* __restrict__ QKV, bf16_t* __restrict__ VT) {
  int jb = blockIdx.x, z = blockIdx.y;
  int b = z >> 3, h = z & 7;
  const bf16_t* src = QKV + (long)b * 1024 * 1536 + 1024 + h * 64;
  bf16_t* dst = VT + (long)z * 65536;
  __shared__ bf16_t t[64][65];
  int tid = threadIdx.x;
#pragma unroll
  for (int i = 0; i < 16; ++i) {
    int l = i * 256 + tid;
    int j = l >> 6, d = l & 63;
    t[d][j] = src[(long)(jb * 64 + j) * 1536 + d];
  }
  __syncthreads();
#pragma unroll
  for (int i = 0; i < 16; ++i) {
    int l = i * 256 + tid;
    int d = l >> 6, j = l & 63;
    dst[(long)d * 1024 + jb * 64 + j] = t[d][j];
  }
}

__global__ __launch_bounds__(256) void dwconv_kernel(const bf16_t* __restrict__ G, const float* __restrict__ dw,
    const float* __restrict__ db, const float* __restrict__ bng, const float* __restrict__ bnb,
    const float* __restrict__ bnm, const float* __restrict__ bnv, bf16_t* __restrict__ out) {
  int n0 = blockIdx.x * 32, c0 = blockIdx.y * 64, b = blockIdx.z;
  __shared__ bf16_t t[62][64];
  __shared__ float dws[31][64];
  int tid = threadIdx.x;
  const bf16_t* src = G + (long)b * 1024 * 1024 + c0;
  // vectorized staging: 62 rows x 64 cols = 496 hbf8 chunks
#pragma unroll
  for (int i = 0; i < 2; ++i) {
    int l = i * 256 + tid;
    if (l < 496) {
      int rr = l >> 3, c8 = (l & 7) * 8;
      int n = n0 - 15 + rr;
      hbf8 v;
      if (n >= 0 && n < 1024) v = *(const hbf8*)(src + (long)n * 1024 + c8);
      else { for (int m = 0; m < 8; ++m) v.h[m] = f2b(0.f); }
      *(hbf8*)&t[rr][c8] = v;
    }
  }
#pragma unroll
  for (int i = 0; i < 8; ++i) {
    int l = i * 256 + tid;
    if (l < 1984) {
      int k = l >> 6, c = l & 63;
      dws[k][c] = dw[(long)(c0 + c) * 31 + k];
    }
  }
  __syncthreads();
  int c = tid & 63, nl = tid >> 6;
  float rs = rsqrtf(bnv[c0 + c] + 1e-5f);
  float sc = rs * bng[c0 + c];
  float ab = (db[c0 + c] - bnm[c0 + c]) * sc + bnb[c0 + c];
#pragma unroll
  for (int j = 0; j < 8; ++j) {
    int rr = nl * 8 + j;
    float s = 0.f;
#pragma unroll
    for (int k = 0; k < 31; ++k) s += b2f(t[rr + k][c]) * dws[k][c];
    float y = s * sc + ab;
    out[((long)b * 1024 + n0 + rr) * 1024 + c0 + c] = f2b(y * sig_(y));
  }
}

// ---------------------------------------------------------------- launch
extern "C" void kernel_launch(void* const* d_in, const int* in_sizes, int n_in,
                              void* d_out, int out_size, void* d_ws, size_t ws_size,
                              hipStream_t stream) {
  auto fail = [&](float code) {
    diag_kernel<<<(out_size + 255) / 256, 256, 0, stream>>>((float*)d_out, out_size, code);
  };
  if (n_in != 34)             { fail(70.f);  return; }
  if (in_sizes[0] != 4194304) { fail(80.f);  return; }

  const float* x     = (const float*)d_in[0];
  const float* f1_g  = (const float*)d_in[1];
  const float* f1_b  = (const float*)d_in[2];
  const float* f1_w1 = (const float*)d_in[3];
  const float* f1_b1 = (const float*)d_in[4];
  const float* f1_w2 = (const float*)d_in[5];
  const float* f1_b2 = (const float*)d_in[6];
  const float* a_g   = (const float*)d_in[7];
  const float* a_b   = (const float*)d_in[8];
  const float* wq    = (const float*)d_in[9];
  const float* wkv   = (const float*)d_in[10];
  const float* wo    = (const float*)d_in[11];
  const float* wo_b  = (const float*)d_in[12];
  const float* rel   = (const float*)d_in[13];
  const float* c_g   = (const float*)d_in[14];
  const float* c_b   = (const float*)d_in[15];
  const float* cw1   = (const float*)d_in[16];
  const float* cb1   = (const float*)d_in[17];
  const float* dwp   = (const float*)d_in[18];
  const float* dbp   = (const float*)d_in[19];
  const float* bn_g  = (const float*)d_in[20];
  const float* bn_b  = (const float*)d_in[21];
  const float* bn_m  = (const float*)d_in[22];
  const float* bn_v  = (const float*)d_in[23];
  const float* cw2   = (const float*)d_in[24];
  const float* cb2   = (const float*)d_in[25];
  const float* f2_g  = (const float*)d_in[26];
  const float* f2_b  = (const float*)d_in[27];
  const float* f2_w1 = (const float*)d_in[28];
  const float* f2_b1 = (const float*)d_in[29];
  const float* f2_w2 = (const float*)d_in[30];
  const float* f2_b2 = (const float*)d_in[31];
  const float* p_g   = (const float*)d_in[32];
  const float* p_b   = (const float*)d_in[33];

  // ---- workspace arena ----
  // X 16.78M | WT 13.63M | D 33.55M {QKV 25.2M + VT 8.4M}/{GLU 16.8M + DWO 16.8M}
  // | E: MID 33.55M | RELP 147K
  char* ws = (char*)d_ws;
  const size_t OFF_X  = 0;
  const size_t OFF_WT = 16777216;
  const size_t OFF_D  = 30408704;
  const size_t OFF_E  = 63963136;
  const size_t relp_off = OFF_E + 33554432;
  if (ws_size < relp_off + 147456ULL) { fail(200.f); return; }

  float*  X   = (float*)(ws + OFF_X);
  bf16_t* WT  = (bf16_t*)(ws + OFF_WT);
  bf16_t* QKV = (bf16_t*)(ws + OFF_D);
  bf16_t* VT  = (bf16_t*)(ws + OFF_D + 25165824);
  bf16_t* GLU = (bf16_t*)(ws + OFF_D);
  bf16_t* DWO = (bf16_t*)(ws + OFF_D + 16777216);
  bf16_t* MID = (bf16_t*)(ws + OFF_E);
  bf16_t* RELP= (bf16_t*)(ws + relp_off);
  bf16_t* H   = (bf16_t*)d_out;   // bf16 scratch inside f32 out buffer
  bf16_t* O   = (bf16_t*)d_out;   // final f32 LN overwrites at the end

  bf16_t* f1_w1t = WT;            bf16_t* f1_w2t = WT + 1048576;
  bf16_t* wqkvt  = WT + 2097152;  // [1536][512]: wq rows 0-511 (pre-scaled), wkv rows 512-1535
  bf16_t* wot    = WT + 2883584;  bf16_t* cw1t   = WT + 3145728;  // column-interleaved
  bf16_t* cw2t   = WT + 4194304;  bf16_t* f2_w1t = WT + 4718592;
  bf16_t* f2_w2t = WT + 5767168;

  auto GA = [](const bf16_t* A, const bf16_t* Bt, const float* bias, bf16_t* C,
               float* resid, const float* srcf, int K, int lda, int ldb, int ldc,
               float alpha, float beta) {
    GemmArgs g{}; g.A = A; g.Bt = Bt; g.bias = bias; g.srcf = srcf; g.C = C; g.resid = resid;
    g.K = K; g.lda = lda; g.ldb = ldb; g.ldc = ldc;
    g.sAb = g.sAh = g.sBb = g.sBh = g.sCb = g.sCh = 0; g.alpha = alpha; g.beta = beta;
    return g;
  };

  // ---- batched weight prep (9 transposes + relpad in ONE dispatch) ----
  {
    PrepJobs P{};
    auto set = [&](int idx, const float* s, bf16_t* d, int R, int C, int start,
                   float sc, int mode) {
      P.src[idx] = s; P.dst[idx] = d; P.R[idx] = R; P.C[idx] = C;
      P.gx[idx] = C / 32; P.start[idx] = start; P.scale[idx] = sc; P.mode[idx] = mode;
    };
    //            src     dst              R     C     start  scale   mode
    set(0, f1_w1, f1_w1t,          512, 2048,    0, 1.f,    0);
    set(1, f1_w2, f1_w2t,         2048,  512, 1024, 1.f,    0);
    set(2, wq,    wqkvt,           512,  512, 2048, 0.125f, 0);
    set(3, wkv,   wqkvt + 262144,  512, 1024, 2304, 1.f,    0);
    set(4, wo,    wot,             512,  512, 2816, 1.f,    0);
    set(5, cw1,   cw1t,            512, 2048, 3072, 1.f,    1);
    set(6, cw2,   cw2t,           1024,  512, 4096, 1.f,    0);
    set(7, f2_w1, f2_w1t,          512, 2048, 4608, 1.f,    0);
    set(8, f2_w2, f2_w2t,         2048,  512, 5632, 1.f,    0);
    set(9, rel,   RELP,           1025,   64, 6656, 1.f,    2);
    P.njobs = 10;
    prep_kernel<<<6944, 256, 0, stream>>>(P);
  }

  // ---- FF1 half-step ----  (LN1 reads x directly; EPI2 writes X = x + 0.5*(...))
  ln_kernel<false><<<8192, 256, 0, stream>>>(x, f1_g, f1_b, H);
  { GemmArgs g = GA(H, f1_w1t, f1_b1, MID, nullptr, nullptr, 512, 512, 512, 2048, 1.f, 0.f);
    gemm_bt<128, 128, 2, 2, 1><<<dim3(16, 64, 1), 256, 0, stream>>>(g); }
  { GemmArgs g = GA(MID, f1_w2t, f1_b2, nullptr, X, x, 2048, 2048, 2048, 512, 1.f, 0.5f);
    gemm_bt<64, 128, 1, 4, 2><<<dim3(4, 128, 1), 256, 0, stream>>>(g); }

  // ---- attention ----
  ln_kernel<false><<<8192, 256, 0, stream>>>(X, a_g, a_b, H);
  { GemmArgs g = GA(H, wqkvt, nullptr, QKV, nullptr, nullptr, 512, 512, 512, 1536, 1.f, 0.f);
    gemm_bt<128, 128, 2, 2, 0><<<dim3(12, 64, 1), 256, 0, stream>>>(g); }   // q|k|v (q scale folded)
  vt_kernel<<<dim3(16, 64), 256, 0, stream>>>(QKV, VT);

  // fused: T=q@rel^T (in-LDS), S = qk^T + bias, wave-local softmax, O = P @ V
  attn_kernel<<<dim3(32, 64), 512, 0, stream>>>(QKV, VT, RELP, O);

  { GemmArgs g = GA(O, wot, wo_b, nullptr, X, nullptr, 512, 512, 512, 512, 1.f, 1.f);
    gemm_bt<64, 128, 1, 4, 2><<<dim3(4, 128, 1), 256, 0, stream>>>(g); }   // x += o@wo + b

  // ---- conv module ----
  ln_kernel<false><<<8192, 256, 0, stream>>>(X, c_g, c_b, H);
  { GemmArgs g = GA(H, cw1t, cb1, GLU, nullptr, nullptr, 512, 512, 512, 1024, 1.f, 0.f);
    gemm_bt<128, 128, 2, 2, 4><<<dim3(16, 64, 1), 256, 0, stream>>>(g); }  // pw1 + bias + GLU
  dwconv_kernel<<<dim3(32, 16, 8), 256, 0, stream>>>(GLU, dwp, dbp, bn_g, bn_b, bn_m, bn_v, DWO);
  { GemmArgs g = GA(DWO, cw2t, cb2, nullptr, X, nullptr, 1024, 1024, 1024, 512, 1.f, 1.f);
    gemm_bt<64, 128, 1, 4, 2><<<dim3(4, 128, 1), 256, 0, stream>>>(g); }   // x += h@cw2 + b

  // ---- FF2 half-step + post-LN (f32 out) ----
  ln_kernel<false><<<8192, 256, 0, stream>>>(X, f2_g, f2_b, H);
  { GemmArgs g = GA(H, f2_w1t, f2_b1, MID, nullptr, nullptr, 512, 512, 512, 2048, 1.f, 0.f);
    gemm_bt<128, 128, 2, 2, 1><<<dim3(16, 64, 1), 256, 0, stream>>>(g); }
  { GemmArgs g = GA(MID, f2_w2t, f2_b2, nullptr, X, nullptr, 2048, 2048, 2048, 512, 1.f, 0.5f);
    gemm_bt<64, 128, 1, 4, 2><<<dim3(4, 128, 1), 256, 0, stream>>>(g); }
  ln_kernel<true><<<8192, 256, 0, stream>>>(X, p_g, p_b, (float*)d_out);
}

// Round 9
// 625.551 us; speedup vs baseline: 1.0108x; 1.0108x over previous
//
#include <hip/hip_runtime.h>
#include <hip/hip_bf16.h>
#include <cstdint>

// Conformer block, MI355X gfx950. f32 inputs, f32 output, bf16 MFMA internals.
// B=8 N=1024 D=512 H=8 DH=64 FF=2048 CI=1024 K=31 MPE=512.
// Round 18: gemm reverted to verified BK=32 loop (BK=64 regressed the fleet
// ~15us); V-transpose folded into QKV gemm epilogue (EPI5 writes VT directly,
// vt_kernel + 50MB traffic eliminated). attn swapped-T + flash softmax kept.

using bf16_t = __hip_bfloat16;
typedef __bf16 bf16x8 __attribute__((ext_vector_type(8)));
typedef float floatx4 __attribute__((ext_vector_type(4)));

struct alignas(16) hbf8 { bf16_t h[8]; };
struct alignas(8)  hbf4 { bf16_t h[4]; };

__device__ __forceinline__ float  b2f(bf16_t h) { return __bfloat162float(h); }
__device__ __forceinline__ bf16_t f2b(float f)  { return __float2bfloat16(f); }
__device__ __forceinline__ float  sig_(float x) { return 1.f / (1.f + __expf(-x)); }

// pack 2 f32 -> 2 bf16 in one u32 (low 16 = a, high = b); pure C (R4-verified)
__device__ __forceinline__ unsigned pkbf(float a, float b) {
  bf16_t ha = f2b(a), hb = f2b(b);
  unsigned short ua, ub;
  __builtin_memcpy(&ua, &ha, 2);
  __builtin_memcpy(&ub, &hb, 2);
  return (unsigned)ua | ((unsigned)ub << 16);
}

// async global->LDS, 16B/lane; LDS dest must be wave-uniform base + lane*16 (m97 pattern)
__device__ __forceinline__ void async16(const void* g, void* l) {
  __builtin_amdgcn_global_load_lds(
      (const __attribute__((address_space(1))) unsigned int*)(uintptr_t)g,
      (__attribute__((address_space(3))) unsigned int*)(uintptr_t)l, 16, 0, 0);
}

// ---------------------------------------------------------------- GEMM (MFMA)
// C[M,N] = A[M,K] @ Bt[N,K]^T   (bf16 operands, k-contiguous, f32 accum)
// EPI 0: C_bf16 = alpha*acc + bias
// EPI 1: C_bf16 = swish(acc + bias)
// EPI 2: resid_f32 = (srcf ? srcf[i] : resid[i]) + beta*(acc+bias)
// EPI 4: GLU: bias idx (j>>1)+(j&1)*1024; even-j lanes write
//        C[i][j>>1] = v * sig(partner v) (cw1t stored column-interleaved)
// EPI 5: QKV: j<1024 -> C[i][j] bf16; j>=1024 (V cols) -> VT (C2) directly:
//        VT[(b*8+h)*65536 + d*1024 + n], h=(j-1024)>>6, d=(j-1024)&63 (hbf4, coalesced)
struct GemmArgs {
  const bf16_t* A; const bf16_t* Bt; const float* bias; const float* srcf;
  bf16_t* C; bf16_t* C2; float* resid;
  int K, lda, ldb, ldc;
  long sAb, sAh, sBb, sBh, sCb, sCh;
  float alpha, beta;
};

template <int BM, int BN, int WR, int WC, int EPI>
__global__ __launch_bounds__(256) void gemm_bt(GemmArgs g) {
  constexpr int FM = BM / (WR * 16);
  constexpr int FN = BN / (WC * 16);
  constexpr int IA = (BM * 4) / 256;
  constexpr int IB = (BN * 4) / 256;
  __shared__ __align__(16) bf16_t As[BM * 32];
  __shared__ __align__(16) bf16_t Bs[BN * 32];
  const int tid = threadIdx.x;
  const int lane = tid & 63, w = tid >> 6;
  // XCD-chunked bijective remap (nwg % 8 == 0 for all our launches)
  int bx = blockIdx.x, by = blockIdx.y;
  {
    const int gx = gridDim.x;
    const int nwg = gx * gridDim.y;
    if ((nwg & 7) == 0 && gridDim.z == 1) {
      int lin = by * gx + bx;
      int lid = (lin & 7) * (nwg >> 3) + (lin >> 3);
      bx = lid % gx; by = lid / gx;
    }
  }
  const int bm0 = by * BM, bn0 = bx * BN;
  const int zb = blockIdx.z >> 3, zh = blockIdx.z & 7;
  const bf16_t* Ab = g.A + (long)zb * g.sAb + (long)zh * g.sAh;
  const bf16_t* Bb = g.Bt + (long)zb * g.sBb + (long)zh * g.sBh;
  const int wm0 = (w / WC) * (FM * 16);
  const int wn0 = (w % WC) * (FN * 16);
  const int lrow = lane & 15, lq = lane >> 4;

  floatx4 acc[FM][FN] = {};

  for (int k0 = 0; k0 < g.K; k0 += 32) {
#pragma unroll
    for (int i = 0; i < IA; ++i) {
      int c = i * 256 + tid;
      int m = c >> 2, kk = (c & 3) * 8;
      async16(Ab + (long)(bm0 + m) * g.lda + (k0 + kk), (char*)As + c * 16);
    }
#pragma unroll
    for (int i = 0; i < IB; ++i) {
      int c = i * 256 + tid;
      int n = bn0 + (c >> 2), kk = (c & 3) * 8;
      async16(Bb + (long)n * g.ldb + (k0 + kk), (char*)Bs + c * 16);
    }
    __syncthreads();   // drains vmcnt before s_barrier (compiler-inserted)
    bf16x8 af[FM], bfr[FN];
#pragma unroll
    for (int fm = 0; fm < FM; ++fm)
      af[fm] = *(const bf16x8*)(As + (wm0 + fm * 16 + lrow) * 32 + lq * 8);
#pragma unroll
    for (int fn = 0; fn < FN; ++fn)
      bfr[fn] = *(const bf16x8*)(Bs + (wn0 + fn * 16 + lrow) * 32 + lq * 8);
#pragma unroll
    for (int fm = 0; fm < FM; ++fm)
#pragma unroll
      for (int fn = 0; fn < FN; ++fn)
        acc[fm][fn] = __builtin_amdgcn_mfma_f32_16x16x32_bf16(af[fm], bfr[fn], acc[fm][fn], 0, 0, 0);
    __syncthreads();
  }

  const int bi = bm0 + wm0 + lq * 4;    // + fm*16 + r
  const int bj = bn0 + wn0 + lrow;      // + fn*16
  if constexpr (EPI == 2) {
    float* R = g.resid;
    const float* S = g.srcf;
#pragma unroll
    for (int fm = 0; fm < FM; ++fm)
#pragma unroll
      for (int fn = 0; fn < FN; ++fn) {
        int j = bj + fn * 16;
        float bv = g.bias ? g.bias[j] : 0.f;
#pragma unroll
        for (int r = 0; r < 4; ++r) {
          long i = bi + fm * 16 + r;
          float base = S ? S[i * g.ldc + j] : R[i * g.ldc + j];
          R[i * g.ldc + j] = base + g.beta * (acc[fm][fn][r] + bv);
        }
      }
  } else if constexpr (EPI == 4) {
    bf16_t* C = g.C;
#pragma unroll
    for (int fm = 0; fm < FM; ++fm)
#pragma unroll
      for (int fn = 0; fn < FN; ++fn) {
        int j = bj + fn * 16;
        float bv = g.bias[(j >> 1) + (j & 1) * 1024];
#pragma unroll
        for (int r = 0; r < 4; ++r) {
          int i = bi + fm * 16 + r;
          float v = acc[fm][fn][r] + bv;
          float gp = __shfl_xor(v, 1);
          if ((j & 1) == 0)
            C[(long)i * g.ldc + (j >> 1)] = f2b(v * sig_(gp));
        }
      }
  } else if constexpr (EPI == 5) {
    bf16_t* C = g.C;
    bf16_t* VTo = g.C2;
#pragma unroll
    for (int fm = 0; fm < FM; ++fm)
#pragma unroll
      for (int fn = 0; fn < FN; ++fn) {
        int j = bj + fn * 16;
        if (j < 1024) {           // q|k -> QKV rows
#pragma unroll
          for (int r = 0; r < 4; ++r) {
            int i = bi + fm * 16 + r;
            C[(long)i * g.ldc + j] = f2b(acc[fm][fn][r]);
          }
        } else {                  // v -> VT directly (4 consecutive i = 8B store)
          int vc = j - 1024;
          int h = vc >> 6, d = vc & 63;
          int ib = bi + fm * 16;          // 4-aligned; b-boundary (1024) never crossed
          int bb = ib >> 10, n = ib & 1023;
          hbf4 o4;
#pragma unroll
          for (int r = 0; r < 4; ++r) o4.h[r] = f2b(acc[fm][fn][r]);
          *(hbf4*)(VTo + (long)(bb * 8 + h) * 65536 + (long)d * 1024 + n) = o4;
        }
      }
  } else {
    bf16_t* C = g.C + (long)zb * g.sCb + (long)zh * g.sCh;
#pragma unroll
    for (int fm = 0; fm < FM; ++fm)
#pragma unroll
      for (int fn = 0; fn < FN; ++fn) {
        int j = bj + fn * 16;
        float bv = g.bias ? g.bias[j] : 0.f;
#pragma unroll
        for (int r = 0; r < 4; ++r) {
          int i = bi + fm * 16 + r;
          float v = acc[fm][fn][r];
          if constexpr (EPI == 0) v = g.alpha * v + bv;
          if constexpr (EPI == 1) { v += bv; v = v * sig_(v); }
          C[(long)i * g.ldc + j] = f2b(v);
        }
      }
  }
}

// ---------------------------------------------------------------- fused attention
// One block = one (z = b*8+h, 32-row i-tile). 512 threads = 8 waves.
// Wave w owns j-slab [w*128, w*128+128).
// Phase 0: T[i][u] via SWAPPED mfma(rel, q): lane holds 4 consecutive u for
//          row i=lane&15 -> packed b64 stores.
// Phase 1: S = Q K^T (regs, K prefetched) + bias gathered from T.
// Phase 2: wave-local softmax (flash rescale deferred to K-reduce).
// Phase 3: unnormalized P -> LDS (XOR-swizzled, aliases T), PV with VT
//          prefetched, K-split partials rescaled+normalized in the reduce.
// QKV: bf16 [(b*1024+n)*1536 + {q:0|k:512} + h*64 + d] (q pre-scaled 1/8; V region unused)
// VT: bf16 [(b*8+h)*65536 + d*1024 + j]
// RELP: bf16 [1152][64] (rows >=1025 zero)
// O: bf16 [(b*1024+i)*512 + h*64 + d]
__global__ __launch_bounds__(512, 4) void attn_kernel(
    const bf16_t* __restrict__ QKV, const bf16_t* __restrict__ VT,
    const bf16_t* __restrict__ RELP, bf16_t* __restrict__ O) {
  constexpr int LDT = 1028;                         // 2056 B row -> 2-bank rotate
  __shared__ __align__(16) bf16_t Tls[32 * LDT];    // 65792 B; aliased: T -> P -> partials
  __shared__ float scr[576];  // [0,288) m_w (stride 9), [288,576) s_w

  const int tid = threadIdx.x;
  const int w = tid >> 6, lane = tid & 63;
  const int lrow = lane & 15, lq = lane >> 4;
  // XCD-chunked remap: 2048 blocks; each XCD gets all 32 i-tiles of 8 z's
  const int lin = blockIdx.y * gridDim.x + blockIdx.x;   // gridDim.x = 32
  const int lid = (lin & 7) * 256 + (lin >> 3);
  const int z = lid >> 5;
  const int i0 = (lid & 31) * 32;
  const int b = z >> 3, zh = z & 7;
  const int j0w = w * 128;

  const bf16_t* Qb  = QKV + ((long)(b * 1024 + i0)) * 1536 + zh * 64;
  const bf16_t* Kb  = QKV + ((long)b * 1024) * 1536 + 512 + zh * 64;
  const bf16_t* VTb = VT + ((long)(b * 8 + zh)) * 65536;

  // Q fragments: af[fm][ks] covers rows fm*16..+15 (lane lrow), k-half ks.
  bf16x8 af[2][2];
#pragma unroll
  for (int fm = 0; fm < 2; ++fm)
#pragma unroll
    for (int ks = 0; ks < 2; ++ks)
      af[fm][ks] = *(const bf16x8*)(Qb + (long)(fm * 16 + lrow) * 1536 + ks * 32 + lq * 8);

  // ---- phase 0: T[i][u] via swapped tiles = mfma(rel, q); packed b64 stores ----
  {
    const int u0w = w * 144;
    bf16x8 rf[18];
#pragma unroll
    for (int fnT = 0; fnT < 9; ++fnT) {
      const int u0 = u0w + fnT * 16;
      if (u0 <= 1024) {
        rf[2 * fnT]     = *(const bf16x8*)(RELP + (long)(u0 + lrow) * 64 + lq * 8);
        rf[2 * fnT + 1] = *(const bf16x8*)(RELP + (long)(u0 + lrow) * 64 + 32 + lq * 8);
      }
    }
#pragma unroll
    for (int fnT = 0; fnT < 9; ++fnT) {
      const int u0 = u0w + fnT * 16;
      if (u0 <= 1024) {
#pragma unroll
        for (int fm = 0; fm < 2; ++fm) {
          floatx4 t4 = {};
          t4 = __builtin_amdgcn_mfma_f32_16x16x32_bf16(rf[2 * fnT],     af[fm][0], t4, 0, 0, 0);
          t4 = __builtin_amdgcn_mfma_f32_16x16x32_bf16(rf[2 * fnT + 1], af[fm][1], t4, 0, 0, 0);
          // lane holds T[i = fm*16+lrow][u = u0+lq*4+r], r=0..3 (consecutive u)
          if (u0 + lq * 4 + 4 <= LDT) {
            uint2 v; v.x = pkbf(t4[0], t4[1]); v.y = pkbf(t4[2], t4[3]);
            *(uint2*)(Tls + (long)(fm * 16 + lrow) * LDT + u0 + lq * 4) = v;
          }
        }
      }
    }
  }

  // K fragment prefetch (issued before the barrier; consumed after)
  bf16x8 kfA[8], kfB[8];
#pragma unroll
  for (int x = 0; x < 8; ++x)
    kfA[x] = *(const bf16x8*)(Kb + (long)(j0w + (x >> 1) * 16 + lrow) * 1536 + (x & 1) * 32 + lq * 8);
#pragma unroll
  for (int x = 0; x < 8; ++x)
    kfB[x] = *(const bf16x8*)(Kb + (long)(j0w + (4 + (x >> 1)) * 16 + lrow) * 1536 + (x & 1) * 32 + lq * 8);
  __syncthreads();   // barrier 1: T visible to all waves

  // ---- phase 1: S = Q K^T (f32 in regs) + bias from T ----
  floatx4 sacc[2][8] = {};
#pragma unroll
  for (int fn = 0; fn < 4; ++fn) {
    sacc[0][fn] = __builtin_amdgcn_mfma_f32_16x16x32_bf16(af[0][0], kfA[2 * fn],     sacc[0][fn], 0, 0, 0);
    sacc[0][fn] = __builtin_amdgcn_mfma_f32_16x16x32_bf16(af[0][1], kfA[2 * fn + 1], sacc[0][fn], 0, 0, 0);
    sacc[1][fn] = __builtin_amdgcn_mfma_f32_16x16x32_bf16(af[1][0], kfA[2 * fn],     sacc[1][fn], 0, 0, 0);
    sacc[1][fn] = __builtin_amdgcn_mfma_f32_16x16x32_bf16(af[1][1], kfA[2 * fn + 1], sacc[1][fn], 0, 0, 0);
  }
#pragma unroll
  for (int fn = 4; fn < 8; ++fn) {
    sacc[0][fn] = __builtin_amdgcn_mfma_f32_16x16x32_bf16(af[0][0], kfB[2 * (fn - 4)],     sacc[0][fn], 0, 0, 0);
    sacc[0][fn] = __builtin_amdgcn_mfma_f32_16x16x32_bf16(af[0][1], kfB[2 * (fn - 4) + 1], sacc[0][fn], 0, 0, 0);
    sacc[1][fn] = __builtin_amdgcn_mfma_f32_16x16x32_bf16(af[1][0], kfB[2 * (fn - 4)],     sacc[1][fn], 0, 0, 0);
    sacc[1][fn] = __builtin_amdgcn_mfma_f32_16x16x32_bf16(af[1][1], kfB[2 * (fn - 4) + 1], sacc[1][fn], 0, 0, 0);
  }

  // rel-pos bias gather from LDS: bias[i][j] = T[i_local][clip(i-j,+-512)+512]
#pragma unroll
  for (int fm = 0; fm < 2; ++fm)
#pragma unroll
    for (int r = 0; r < 4; ++r) {
      const int il = fm * 16 + lq * 4 + r;
      const bf16_t* trow = Tls + il * LDT + 512;
      const int tb = i0 + il - j0w - lrow;
#pragma unroll
      for (int fn = 0; fn < 8; ++fn) {
        int t = tb - fn * 16;
        t = t < -512 ? -512 : (t > 512 ? 512 : t);
        sacc[fm][fn][r] += b2f(trow[t]);
      }
    }

  // ---- phase 2: wave-local softmax (flash rescale deferred to reduce) ----
  float rmax[2][4];
#pragma unroll
  for (int fm = 0; fm < 2; ++fm)
#pragma unroll
    for (int r = 0; r < 4; ++r) {
      float m = sacc[fm][0][r];
#pragma unroll
      for (int fn = 1; fn < 8; ++fn) m = fmaxf(m, sacc[fm][fn][r]);
      rmax[fm][r] = m;
    }
#pragma unroll
  for (int off = 1; off < 16; off <<= 1)   // reduce across the 16 j-lanes (lrow)
#pragma unroll
    for (int fm = 0; fm < 2; ++fm)
#pragma unroll
      for (int r = 0; r < 4; ++r)
        rmax[fm][r] = fmaxf(rmax[fm][r], __shfl_xor(rmax[fm][r], off));
  if (lrow == 0)
#pragma unroll
    for (int fm = 0; fm < 2; ++fm)
#pragma unroll
      for (int r = 0; r < 4; ++r)
        scr[(fm * 16 + lq * 4 + r) * 9 + w] = rmax[fm][r];

  float rsum[2][4];
#pragma unroll
  for (int fm = 0; fm < 2; ++fm)
#pragma unroll
    for (int r = 0; r < 4; ++r) {
      float s = 0.f;
#pragma unroll
      for (int fn = 0; fn < 8; ++fn) {
        float e = __expf(sacc[fm][fn][r] - rmax[fm][r]);
        sacc[fm][fn][r] = e;
        s += e;
      }
      rsum[fm][r] = s;
    }
#pragma unroll
  for (int off = 1; off < 16; off <<= 1)
#pragma unroll
    for (int fm = 0; fm < 2; ++fm)
#pragma unroll
      for (int r = 0; r < 4; ++r)
        rsum[fm][r] += __shfl_xor(rsum[fm][r], off);
  if (lrow == 0)
#pragma unroll
    for (int fm = 0; fm < 2; ++fm)
#pragma unroll
      for (int r = 0; r < 4; ++r)
        scr[288 + (fm * 16 + lq * 4 + r) * 9 + w] = rsum[fm][r];

  // VT prefetch, first half (ks 0,1)
  bf16x8 vfA[8];
#pragma unroll
  for (int x = 0; x < 8; ++x)   // x = ks*4 + fd, ks in {0,1}
    vfA[x] = *(const bf16x8*)(VTb + (long)((x & 3) * 16 + lrow) * 1024 + j0w + (x >> 2) * 32 + lq * 8);

  __syncthreads();   // barrier 2: all T gathers done -> safe to alias P over T

  // ---- phase 3a: unnormalized P -> LDS (XOR swizzle ^((i&7)<<4); wave-local) ----
#pragma unroll
  for (int fm = 0; fm < 2; ++fm)
#pragma unroll
    for (int fn = 0; fn < 8; ++fn)
#pragma unroll
      for (int r = 0; r < 4; ++r) {
        const int i = fm * 16 + lq * 4 + r;
        const int j = j0w + fn * 16 + lrow;
        const unsigned boff = (unsigned)(i * 2048 + j * 2) ^ ((unsigned)(i & 7) << 4);
        *(bf16_t*)((char*)Tls + boff) = f2b(sacc[fm][fn][r]);
      }
  // no barrier needed: each wave reads back only its own slab

  // VT prefetch, second half (ks 2,3)
  bf16x8 vfB[8];
#pragma unroll
  for (int x = 0; x < 8; ++x)   // x = ks*4 + fd, ks in {2,3}
    vfB[x] = *(const bf16x8*)(VTb + (long)((x & 3) * 16 + lrow) * 1024 + j0w + 64 + (x >> 2) * 32 + lq * 8);

  // ---- phase 3b: O partials = P_slab @ V_slab ----
  floatx4 oacc[2][4] = {};
#pragma unroll
  for (int ks = 0; ks < 4; ++ks) {
    const int j = j0w + ks * 32;
    bf16x8 ap[2];
#pragma unroll
    for (int fm = 0; fm < 2; ++fm) {
      const int i = fm * 16 + lrow;
      const unsigned boff = (unsigned)(i * 2048 + (j + lq * 8) * 2) ^ ((unsigned)(i & 7) << 4);
      ap[fm] = *(const bf16x8*)((char*)Tls + boff);
    }
#pragma unroll
    for (int fd = 0; fd < 4; ++fd) {
      bf16x8 bv = (ks < 2) ? vfA[(ks << 2) | fd] : vfB[((ks - 2) << 2) | fd];
      oacc[0][fd] = __builtin_amdgcn_mfma_f32_16x16x32_bf16(ap[0], bv, oacc[0][fd], 0, 0, 0);
      oacc[1][fd] = __builtin_amdgcn_mfma_f32_16x16x32_bf16(ap[1], bv, oacc[1][fd], 0, 0, 0);
    }
  }
  __syncthreads();   // barrier 3: all PV reads of P done -> overwrite with partials

  // partials: per-wave f32 [i][64] at float offset w*2048 (re-aliases LDS)
  {
    float* part = (float*)Tls + w * 2048;
#pragma unroll
    for (int fm = 0; fm < 2; ++fm)
#pragma unroll
      for (int fd = 0; fd < 4; ++fd)
#pragma unroll
        for (int r = 0; r < 4; ++r)
          part[(fm * 16 + lq * 4 + r) * 64 + fd * 16 + lrow] = oacc[fm][fd][r];
  }
  __syncthreads();   // barrier 4

  // K-reduce 8 partials with flash rescale + normalization, write O
  {
    const int i = tid >> 4;
    const int d0 = (tid & 15) * 4;
    float mw[8], sw[8];
#pragma unroll
    for (int ww = 0; ww < 8; ++ww) {
      mw[ww] = scr[i * 9 + ww];
      sw[ww] = scr[288 + i * 9 + ww];
    }
    float M = mw[0];
#pragma unroll
    for (int ww = 1; ww < 8; ++ww) M = fmaxf(M, mw[ww]);
    float fac[8]; float tot = 0.f;
#pragma unroll
    for (int ww = 0; ww < 8; ++ww) { fac[ww] = __expf(mw[ww] - M); tot += sw[ww] * fac[ww]; }
    const float inv = 1.f / tot;
    floatx4 s = {};
#pragma unroll
    for (int ww = 0; ww < 8; ++ww) {
      floatx4 p = *(const floatx4*)((const float*)Tls + ww * 2048 + i * 64 + d0);
      s += p * fac[ww];
    }
    hbf4 o4;
#pragma unroll
    for (int m = 0; m < 4; ++m) o4.h[m] = f2b(s[m] * inv);
    *(hbf4*)(O + (long)(b * 1024 + i0 + i) * 512 + zh * 64 + d0) = o4;
  }
}

// ---------------------------------------------------------------- glue kernels
__global__ __launch_bounds__(256) void diag_kernel(float* __restrict__ out, long n, float v) {
  long i = (long)blockIdx.x * 256 + threadIdx.x;
  if (i < n) out[i] = v;
}

// batched weight prep: 9 transposes (f32->bf16, optional scale / GLU perm) + relpad
struct PrepJobs {
  const float* src[10];
  bf16_t*      dst[10];
  int R[10], C[10], gx[10], start[10];
  float scale[10];
  int   mode[10];   // 0 transpose, 1 transpose+GLU col-interleave, 2 relpad
  int   njobs;
};

__global__ __launch_bounds__(256) void prep_kernel(PrepJobs P) {
  __shared__ float t[32][33];
  const int bid = blockIdx.x;
  int j = 0;
  while (j + 1 < P.njobs && bid >= P.start[j + 1]) ++j;
  const int tile = bid - P.start[j];
  const int tid = threadIdx.x;
  if (P.mode[j] == 2) {   // relpad: [1025,64] f32 -> [1152,64] bf16 (zero tail)
    int i = tile * 256 + tid;
    if (i < 73728) {
      int r = i >> 6, c = i & 63;
      P.dst[j][i] = (r < 1025) ? f2b(P.src[j][r * 64 + c]) : f2b(0.f);
    }
    return;
  }
  const int gx = P.gx[j];
  const int c0 = (tile % gx) * 32, r0 = (tile / gx) * 32;
  const int C = P.C[j], R = P.R[j];
  const float scale = P.scale[j];
  const int tx = tid & 31, ty = tid >> 5;
#pragma unroll
  for (int i = 0; i < 4; ++i)
    t[ty + i * 8][tx] = P.src[j][(long)(r0 + ty + i * 8) * C + c0 + tx];
  __syncthreads();
#pragma unroll
  for (int i = 0; i < 4; ++i) {
    int c = c0 + ty + i * 8;
    int row = (P.mode[j] == 1) ? ((c < 1024) ? 2 * c : 2 * (c - 1024) + 1) : c;
    P.dst[j][(long)row * R + r0 + tx] = f2b(t[tx][ty + i * 8] * scale);
  }
}

template <bool F32OUT>
__global__ __launch_bounds__(256) void ln_kernel(const float* __restrict__ X, const float* __restrict__ gam,
                                                 const float* __restrict__ bet, void* __restrict__ outv) {
  int row = blockIdx.x, tid = threadIdx.x;
  const float* x = X + (long)row * 512;
  float a = x[tid], b = x[tid + 256];
  float s = a + b, q = a * a + b * b;
  for (int off = 32; off; off >>= 1) { s += __shfl_down(s, off); q += __shfl_down(q, off); }
  __shared__ float red[8];
  int w = tid >> 6;
  if ((tid & 63) == 0) { red[w] = s; red[w + 4] = q; }
  __syncthreads();
  float ts = red[0] + red[1] + red[2] + red[3];
  float tq = red[4] + red[5] + red[6] + red[7];
  float mean = ts * (1.f / 512.f);
  float var = tq * (1.f / 512.f) - mean * mean;
  float rs = rsqrtf(var + 1e-5f);
  float o0 = (a - mean) * rs * gam[tid]       + bet[tid];
  float o1 = (b - mean) * rs * gam[tid + 256] + bet[tid + 256];
  if constexpr (F32OUT) {
    float* out = (float*)outv;
    out[(long)row * 512 + tid]       = o0;
    out[(long)row * 512 + tid + 256] = o1;
  } else {
    bf16_t* out = (bf16_t*)outv;
    out[(long)row * 512 + tid]       = f2b(o0);
    out[(long)row * 512 + tid + 256] = f2b(o1);
  }
}

__global__ __launch_bounds__(256) void dwconv_kernel(const bf16_t* __restrict__ G, const float* __restrict__ dw,
    const float* __restrict__ db, const float* __restrict__ bng, const float* __restrict__ bnb,
    const float* __restrict__ bnm, const float* __restrict__ bnv, bf16_t* __restrict__ out) {
  int n0 = blockIdx.x * 32, c0 = blockIdx.y * 64, b = blockIdx.z;
  __shared__ bf16_t t[62][64];
  __shared__ float dws[31][64];
  int tid = threadIdx.x;
  const bf16_t* src = G + (long)b * 1024 * 1024 + c0;
  // vectorized staging: 62 rows x 64 cols = 496 hbf8 chunks
#pragma unroll
  for (int i = 0; i < 2; ++i) {
    int l = i * 256 + tid;
    if (l < 496) {
      int rr = l >> 3, c8 = (l & 7) * 8;
      int n = n0 - 15 + rr;
      hbf8 v;
      if (n >= 0 && n < 1024) v = *(const hbf8*)(src + (long)n * 1024 + c8);
      else { for (int m = 0; m < 8; ++m) v.h[m] = f2b(0.f); }
      *(hbf8*)&t[rr][c8] = v;
    }
  }
#pragma unroll
  for (int i = 0; i < 8; ++i) {
    int l = i * 256 + tid;
    if (l < 1984) {
      int k = l >> 6, c = l & 63;
      dws[k][c] = dw[(long)(c0 + c) * 31 + k];
    }
  }
  __syncthreads();
  int c = tid & 63, nl = tid >> 6;
  float rs = rsqrtf(bnv[c0 + c] + 1e-5f);
  float sc = rs * bng[c0 + c];
  float ab = (db[c0 + c] - bnm[c0 + c]) * sc + bnb[c0 + c];
#pragma unroll
  for (int j = 0; j < 8; ++j) {
    int rr = nl * 8 + j;
    float s = 0.f;
#pragma unroll
    for (int k = 0; k < 31; ++k) s += b2f(t[rr + k][c]) * dws[k][c];
    float y = s * sc + ab;
    out[((long)b * 1024 + n0 + rr) * 1024 + c0 + c] = f2b(y * sig_(y));
  }
}

// ---------------------------------------------------------------- launch
extern "C" void kernel_launch(void* const* d_in, const int* in_sizes, int n_in,
                              void* d_out, int out_size, void* d_ws, size_t ws_size,
                              hipStream_t stream) {
  auto fail = [&](float code) {
    diag_kernel<<<(out_size + 255) / 256, 256, 0, stream>>>((float*)d_out, out_size, code);
  };
  if (n_in != 34)             { fail(70.f);  return; }
  if (in_sizes[0] != 4194304) { fail(80.f);  return; }

  const float* x     = (const float*)d_in[0];
  const float* f1_g  = (const float*)d_in[1];
  const float* f1_b  = (const float*)d_in[2];
  const float* f1_w1 = (const float*)d_in[3];
  const float* f1_b1 = (const float*)d_in[4];
  const float* f1_w2 = (const float*)d_in[5];
  const float* f1_b2 = (const float*)d_in[6];
  const float* a_g   = (const float*)d_in[7];
  const float* a_b   = (const float*)d_in[8];
  const float* wq    = (const float*)d_in[9];
  const float* wkv   = (const float*)d_in[10];
  const float* wo    = (const float*)d_in[11];
  const float* wo_b  = (const float*)d_in[12];
  const float* rel   = (const float*)d_in[13];
  const float* c_g   = (const float*)d_in[14];
  const float* c_b   = (const float*)d_in[15];
  const float* cw1   = (const float*)d_in[16];
  const float* cb1   = (const float*)d_in[17];
  const float* dwp   = (const float*)d_in[18];
  const float* dbp   = (const float*)d_in[19];
  const float* bn_g  = (const float*)d_in[20];
  const float* bn_b  = (const float*)d_in[21];
  const float* bn_m  = (const float*)d_in[22];
  const float* bn_v  = (const float*)d_in[23];
  const float* cw2   = (const float*)d_in[24];
  const float* cb2   = (const float*)d_in[25];
  const float* f2_g  = (const float*)d_in[26];
  const float* f2_b  = (const float*)d_in[27];
  const float* f2_w1 = (const float*)d_in[28];
  const float* f2_b1 = (const float*)d_in[29];
  const float* f2_w2 = (const float*)d_in[30];
  const float* f2_b2 = (const float*)d_in[31];
  const float* p_g   = (const float*)d_in[32];
  const float* p_b   = (const float*)d_in[33];

  // ---- workspace arena ----
  // X 16.78M | WT 13.63M | D 33.55M {QKV 25.2M + VT 8.4M}/{GLU 16.8M + DWO 16.8M}
  // | E: MID 33.55M | RELP 147K
  char* ws = (char*)d_ws;
  const size_t OFF_X  = 0;
  const size_t OFF_WT = 16777216;
  const size_t OFF_D  = 30408704;
  const size_t OFF_E  = 63963136;
  const size_t relp_off = OFF_E + 33554432;
  if (ws_size < relp_off + 147456ULL) { fail(200.f); return; }

  float*  X   = (float*)(ws + OFF_X);
  bf16_t* WT  = (bf16_t*)(ws + OFF_WT);
  bf16_t* QKV = (bf16_t*)(ws + OFF_D);
  bf16_t* VT  = (bf16_t*)(ws + OFF_D + 25165824);
  bf16_t* GLU = (bf16_t*)(ws + OFF_D);
  bf16_t* DWO = (bf16_t*)(ws + OFF_D + 16777216);
  bf16_t* MID = (bf16_t*)(ws + OFF_E);
  bf16_t* RELP= (bf16_t*)(ws + relp_off);
  bf16_t* H   = (bf16_t*)d_out;   // bf16 scratch inside f32 out buffer
  bf16_t* O   = (bf16_t*)d_out;   // final f32 LN overwrites at the end

  bf16_t* f1_w1t = WT;            bf16_t* f1_w2t = WT + 1048576;
  bf16_t* wqkvt  = WT + 2097152;  // [1536][512]: wq rows 0-511 (pre-scaled), wkv rows 512-1535
  bf16_t* wot    = WT + 2883584;  bf16_t* cw1t   = WT + 3145728;  // column-interleaved
  bf16_t* cw2t   = WT + 4194304;  bf16_t* f2_w1t = WT + 4718592;
  bf16_t* f2_w2t = WT + 5767168;

  auto GA = [](const bf16_t* A, const bf16_t* Bt, const float* bias, bf16_t* C,
               float* resid, const float* srcf, int K, int lda, int ldb, int ldc,
               float alpha, float beta) {
    GemmArgs g{}; g.A = A; g.Bt = Bt; g.bias = bias; g.srcf = srcf; g.C = C; g.C2 = nullptr;
    g.resid = resid;
    g.K = K; g.lda = lda; g.ldb = ldb; g.ldc = ldc;
    g.sAb = g.sAh = g.sBb = g.sBh = g.sCb = g.sCh = 0; g.alpha = alpha; g.beta = beta;
    return g;
  };

  // ---- batched weight prep (9 transposes + relpad in ONE dispatch) ----
  {
    PrepJobs P{};
    auto set = [&](int idx, const float* s, bf16_t* d, int R, int C, int start,
                   float sc, int mode) {
      P.src[idx] = s; P.dst[idx] = d; P.R[idx] = R; P.C[idx] = C;
      P.gx[idx] = C / 32; P.start[idx] = start; P.scale[idx] = sc; P.mode[idx] = mode;
    };
    //            src     dst              R     C     start  scale   mode
    set(0, f1_w1, f1_w1t,          512, 2048,    0, 1.f,    0);
    set(1, f1_w2, f1_w2t,         2048,  512, 1024, 1.f,    0);
    set(2, wq,    wqkvt,           512,  512, 2048, 0.125f, 0);
    set(3, wkv,   wqkvt + 262144,  512, 1024, 2304, 1.f,    0);
    set(4, wo,    wot,             512,  512, 2816, 1.f,    0);
    set(5, cw1,   cw1t,            512, 2048, 3072, 1.f,    1);
    set(6, cw2,   cw2t,           1024,  512, 4096, 1.f,    0);
    set(7, f2_w1, f2_w1t,          512, 2048, 4608, 1.f,    0);
    set(8, f2_w2, f2_w2t,         2048,  512, 5632, 1.f,    0);
    set(9, rel,   RELP,           1025,   64, 6656, 1.f,    2);
    P.njobs = 10;
    prep_kernel<<<6944, 256, 0, stream>>>(P);
  }

  // ---- FF1 half-step ----  (LN1 reads x directly; EPI2 writes X = x + 0.5*(...))
  ln_kernel<false><<<8192, 256, 0, stream>>>(x, f1_g, f1_b, H);
  { GemmArgs g = GA(H, f1_w1t, f1_b1, MID, nullptr, nullptr, 512, 512, 512, 2048, 1.f, 0.f);
    gemm_bt<128, 128, 2, 2, 1><<<dim3(16, 64, 1), 256, 0, stream>>>(g); }
  { GemmArgs g = GA(MID, f1_w2t, f1_b2, nullptr, X, x, 2048, 2048, 2048, 512, 1.f, 0.5f);
    gemm_bt<64, 128, 1, 4, 2><<<dim3(4, 128, 1), 256, 0, stream>>>(g); }

  // ---- attention ----
  ln_kernel<false><<<8192, 256, 0, stream>>>(X, a_g, a_b, H);
  { GemmArgs g = GA(H, wqkvt, nullptr, QKV, nullptr, nullptr, 512, 512, 512, 1536, 1.f, 0.f);
    g.C2 = VT;   // V columns written transposed, directly
    gemm_bt<128, 128, 2, 2, 5><<<dim3(12, 64, 1), 256, 0, stream>>>(g); }   // q|k -> QKV, v -> VT

  // fused: T=q@rel^T (in-LDS), S = qk^T + bias, wave-local softmax, O = P @ V
  attn_kernel<<<dim3(32, 64), 512, 0, stream>>>(QKV, VT, RELP, O);

  { GemmArgs g = GA(O, wot, wo_b, nullptr, X, nullptr, 512, 512, 512, 512, 1.f, 1.f);
    gemm_bt<64, 128, 1, 4, 2><<<dim3(4, 128, 1), 256, 0, stream>>>(g); }   // x += o@wo + b

  // ---- conv module ----
  ln_kernel<false><<<8192, 256, 0, stream>>>(X, c_g, c_b, H);
  { GemmArgs g = GA(H, cw1t, cb1, GLU, nullptr, nullptr, 512, 512, 512, 1024, 1.f, 0.f);
    gemm_bt<128, 128, 2, 2, 4><<<dim3(16, 64, 1), 256, 0, stream>>>(g); }  // pw1 + bias + GLU
  dwconv_kernel<<<dim3(32, 16, 8), 256, 0, stream>>>(GLU, dwp, dbp, bn_g, bn_b, bn_m, bn_v, DWO);
  { GemmArgs g = GA(DWO, cw2t, cb2, nullptr, X, nullptr, 1024, 1024, 1024, 512, 1.f, 1.f);
    gemm_bt<64, 128, 1, 4, 2><<<dim3(4, 128, 1), 256, 0, stream>>>(g); }   // x += h@cw2 + b

  // ---- FF2 half-step + post-LN (f32 out) ----
  ln_kernel<false><<<8192, 256, 0, stream>>>(X, f2_g, f2_b, H);
  { GemmArgs g = GA(H, f2_w1t, f2_b1, MID, nullptr, nullptr, 512, 512, 512, 2048, 1.f, 0.f);
    gemm_bt<128, 128, 2, 2, 1><<<dim3(16, 64, 1), 256, 0, stream>>>(g); }
  { GemmArgs g = GA(MID, f2_w2t, f2_b2, nullptr, X, nullptr, 2048, 2048, 2048, 512, 1.f, 0.5f);
    gemm_bt<64, 128, 1, 4, 2><<<dim3(4, 128, 1), 256, 0, stream>>>(g); }
  ln_kernel<true><<<8192, 256, 0, stream>>>(X, p_g, p_b, (float*)d_out);
}

// Round 10
// 610.851 us; speedup vs baseline: 1.0351x; 1.0241x over previous
//
#include <hip/hip_runtime.h>
#include <hip/hip_bf16.h>
#include <cstdint>

// Conformer block, MI355X gfx950. f32 inputs, f32 output, bf16 MFMA internals.
// B=8 N=1024 D=512 H=8 DH=64 FF=2048 CI=1024 K=31 MPE=512.
// Round 19: EPI5 reverted (scattered 8B VT stores cost more than vt_kernel's
// coalesced transpose; R8 post-mortem) — QKV gemm writes full 1536 width,
// vt_kernel restored. NEW: s_setprio(1) around attn MFMA clusters (T5,
// +4-7% on attn-shaped kernels per m191). BK=32 gemm, swapped-T attn,
// flash softmax, dwconv-vec, batched prep all retained.

using bf16_t = __hip_bfloat16;
typedef __bf16 bf16x8 __attribute__((ext_vector_type(8)));
typedef float floatx4 __attribute__((ext_vector_type(4)));

struct alignas(16) hbf8 { bf16_t h[8]; };
struct alignas(8)  hbf4 { bf16_t h[4]; };

__device__ __forceinline__ float  b2f(bf16_t h) { return __bfloat162float(h); }
__device__ __forceinline__ bf16_t f2b(float f)  { return __float2bfloat16(f); }
__device__ __forceinline__ float  sig_(float x) { return 1.f / (1.f + __expf(-x)); }

// pack 2 f32 -> 2 bf16 in one u32 (low 16 = a, high = b); pure C (R4-verified)
__device__ __forceinline__ unsigned pkbf(float a, float b) {
  bf16_t ha = f2b(a), hb = f2b(b);
  unsigned short ua, ub;
  __builtin_memcpy(&ua, &ha, 2);
  __builtin_memcpy(&ub, &hb, 2);
  return (unsigned)ua | ((unsigned)ub << 16);
}

// async global->LDS, 16B/lane; LDS dest must be wave-uniform base + lane*16 (m97 pattern)
__device__ __forceinline__ void async16(const void* g, void* l) {
  __builtin_amdgcn_global_load_lds(
      (const __attribute__((address_space(1))) unsigned int*)(uintptr_t)g,
      (__attribute__((address_space(3))) unsigned int*)(uintptr_t)l, 16, 0, 0);
}

// ---------------------------------------------------------------- GEMM (MFMA)
// C[M,N] = A[M,K] @ Bt[N,K]^T   (bf16 operands, k-contiguous, f32 accum)
// EPI 0: C_bf16 = alpha*acc + bias
// EPI 1: C_bf16 = swish(acc + bias)
// EPI 2: resid_f32 = (srcf ? srcf[i] : resid[i]) + beta*(acc+bias)
// EPI 4: GLU: bias idx (j>>1)+(j&1)*1024; even-j lanes write
//        C[i][j>>1] = v * sig(partner v) (cw1t stored column-interleaved)
struct GemmArgs {
  const bf16_t* A; const bf16_t* Bt; const float* bias; const float* srcf;
  bf16_t* C; float* resid;
  int K, lda, ldb, ldc;
  long sAb, sAh, sBb, sBh, sCb, sCh;
  float alpha, beta;
};

template <int BM, int BN, int WR, int WC, int EPI>
__global__ __launch_bounds__(256) void gemm_bt(GemmArgs g) {
  constexpr int FM = BM / (WR * 16);
  constexpr int FN = BN / (WC * 16);
  constexpr int IA = (BM * 4) / 256;
  constexpr int IB = (BN * 4) / 256;
  __shared__ __align__(16) bf16_t As[BM * 32];
  __shared__ __align__(16) bf16_t Bs[BN * 32];
  const int tid = threadIdx.x;
  const int lane = tid & 63, w = tid >> 6;
  // XCD-chunked bijective remap (nwg % 8 == 0 for all our launches)
  int bx = blockIdx.x, by = blockIdx.y;
  {
    const int gx = gridDim.x;
    const int nwg = gx * gridDim.y;
    if ((nwg & 7) == 0 && gridDim.z == 1) {
      int lin = by * gx + bx;
      int lid = (lin & 7) * (nwg >> 3) + (lin >> 3);
      bx = lid % gx; by = lid / gx;
    }
  }
  const int bm0 = by * BM, bn0 = bx * BN;
  const int zb = blockIdx.z >> 3, zh = blockIdx.z & 7;
  const bf16_t* Ab = g.A + (long)zb * g.sAb + (long)zh * g.sAh;
  const bf16_t* Bb = g.Bt + (long)zb * g.sBb + (long)zh * g.sBh;
  const int wm0 = (w / WC) * (FM * 16);
  const int wn0 = (w % WC) * (FN * 16);
  const int lrow = lane & 15, lq = lane >> 4;

  floatx4 acc[FM][FN] = {};

  for (int k0 = 0; k0 < g.K; k0 += 32) {
#pragma unroll
    for (int i = 0; i < IA; ++i) {
      int c = i * 256 + tid;
      int m = c >> 2, kk = (c & 3) * 8;
      async16(Ab + (long)(bm0 + m) * g.lda + (k0 + kk), (char*)As + c * 16);
    }
#pragma unroll
    for (int i = 0; i < IB; ++i) {
      int c = i * 256 + tid;
      int n = bn0 + (c >> 2), kk = (c & 3) * 8;
      async16(Bb + (long)n * g.ldb + (k0 + kk), (char*)Bs + c * 16);
    }
    __syncthreads();   // drains vmcnt before s_barrier (compiler-inserted)
    bf16x8 af[FM], bfr[FN];
#pragma unroll
    for (int fm = 0; fm < FM; ++fm)
      af[fm] = *(const bf16x8*)(As + (wm0 + fm * 16 + lrow) * 32 + lq * 8);
#pragma unroll
    for (int fn = 0; fn < FN; ++fn)
      bfr[fn] = *(const bf16x8*)(Bs + (wn0 + fn * 16 + lrow) * 32 + lq * 8);
#pragma unroll
    for (int fm = 0; fm < FM; ++fm)
#pragma unroll
      for (int fn = 0; fn < FN; ++fn)
        acc[fm][fn] = __builtin_amdgcn_mfma_f32_16x16x32_bf16(af[fm], bfr[fn], acc[fm][fn], 0, 0, 0);
    __syncthreads();
  }

  const int bi = bm0 + wm0 + lq * 4;    // + fm*16 + r
  const int bj = bn0 + wn0 + lrow;      // + fn*16
  if constexpr (EPI == 2) {
    float* R = g.resid;
    const float* S = g.srcf;
#pragma unroll
    for (int fm = 0; fm < FM; ++fm)
#pragma unroll
      for (int fn = 0; fn < FN; ++fn) {
        int j = bj + fn * 16;
        float bv = g.bias ? g.bias[j] : 0.f;
#pragma unroll
        for (int r = 0; r < 4; ++r) {
          long i = bi + fm * 16 + r;
          float base = S ? S[i * g.ldc + j] : R[i * g.ldc + j];
          R[i * g.ldc + j] = base + g.beta * (acc[fm][fn][r] + bv);
        }
      }
  } else if constexpr (EPI == 4) {
    bf16_t* C = g.C;
#pragma unroll
    for (int fm = 0; fm < FM; ++fm)
#pragma unroll
      for (int fn = 0; fn < FN; ++fn) {
        int j = bj + fn * 16;
        float bv = g.bias[(j >> 1) + (j & 1) * 1024];
#pragma unroll
        for (int r = 0; r < 4; ++r) {
          int i = bi + fm * 16 + r;
          float v = acc[fm][fn][r] + bv;
          float gp = __shfl_xor(v, 1);
          if ((j & 1) == 0)
            C[(long)i * g.ldc + (j >> 1)] = f2b(v * sig_(gp));
        }
      }
  } else {
    bf16_t* C = g.C + (long)zb * g.sCb + (long)zh * g.sCh;
#pragma unroll
    for (int fm = 0; fm < FM; ++fm)
#pragma unroll
      for (int fn = 0; fn < FN; ++fn) {
        int j = bj + fn * 16;
        float bv = g.bias ? g.bias[j] : 0.f;
#pragma unroll
        for (int r = 0; r < 4; ++r) {
          int i = bi + fm * 16 + r;
          float v = acc[fm][fn][r];
          if constexpr (EPI == 0) v = g.alpha * v + bv;
          if constexpr (EPI == 1) { v += bv; v = v * sig_(v); }
          C[(long)i * g.ldc + j] = f2b(v);
        }
      }
  }
}

// ---------------------------------------------------------------- fused attention
// One block = one (z = b*8+h, 32-row i-tile). 512 threads = 8 waves.
// Wave w owns j-slab [w*128, w*128+128).
// Phase 0: T[i][u] via SWAPPED mfma(rel, q): lane holds 4 consecutive u for
//          row i=lane&15 -> packed b64 stores.
// Phase 1: S = Q K^T (regs, K prefetched) + bias gathered from T. [setprio 1]
// Phase 2: wave-local softmax (flash rescale deferred to K-reduce).
// Phase 3: unnormalized P -> LDS (XOR-swizzled, aliases T), PV with VT
//          prefetched [setprio 1], K-split partials rescaled in the reduce.
// QKV: bf16 [(b*1024+n)*1536 + {q:0|k:512|v:1024} + h*64 + d] (q pre-scaled 1/8)
// VT: bf16 [(b*8+h)*65536 + d*1024 + j]
// RELP: bf16 [1152][64] (rows >=1025 zero)
// O: bf16 [(b*1024+i)*512 + h*64 + d]
__global__ __launch_bounds__(512, 4) void attn_kernel(
    const bf16_t* __restrict__ QKV, const bf16_t* __restrict__ VT,
    const bf16_t* __restrict__ RELP, bf16_t* __restrict__ O) {
  constexpr int LDT = 1028;                         // 2056 B row -> 2-bank rotate
  __shared__ __align__(16) bf16_t Tls[32 * LDT];    // 65792 B; aliased: T -> P -> partials
  __shared__ float scr[576];  // [0,288) m_w (stride 9), [288,576) s_w

  const int tid = threadIdx.x;
  const int w = tid >> 6, lane = tid & 63;
  const int lrow = lane & 15, lq = lane >> 4;
  // XCD-chunked remap: 2048 blocks; each XCD gets all 32 i-tiles of 8 z's
  const int lin = blockIdx.y * gridDim.x + blockIdx.x;   // gridDim.x = 32
  const int lid = (lin & 7) * 256 + (lin >> 3);
  const int z = lid >> 5;
  const int i0 = (lid & 31) * 32;
  const int b = z >> 3, zh = z & 7;
  const int j0w = w * 128;

  const bf16_t* Qb  = QKV + ((long)(b * 1024 + i0)) * 1536 + zh * 64;
  const bf16_t* Kb  = QKV + ((long)b * 1024) * 1536 + 512 + zh * 64;
  const bf16_t* VTb = VT + ((long)(b * 8 + zh)) * 65536;

  // Q fragments: af[fm][ks] covers rows fm*16..+15 (lane lrow), k-half ks.
  bf16x8 af[2][2];
#pragma unroll
  for (int fm = 0; fm < 2; ++fm)
#pragma unroll
    for (int ks = 0; ks < 2; ++ks)
      af[fm][ks] = *(const bf16x8*)(Qb + (long)(fm * 16 + lrow) * 1536 + ks * 32 + lq * 8);

  // ---- phase 0: T[i][u] via swapped tiles = mfma(rel, q); packed b64 stores ----
  {
    const int u0w = w * 144;
    bf16x8 rf[18];
#pragma unroll
    for (int fnT = 0; fnT < 9; ++fnT) {
      const int u0 = u0w + fnT * 16;
      if (u0 <= 1024) {
        rf[2 * fnT]     = *(const bf16x8*)(RELP + (long)(u0 + lrow) * 64 + lq * 8);
        rf[2 * fnT + 1] = *(const bf16x8*)(RELP + (long)(u0 + lrow) * 64 + 32 + lq * 8);
      }
    }
#pragma unroll
    for (int fnT = 0; fnT < 9; ++fnT) {
      const int u0 = u0w + fnT * 16;
      if (u0 <= 1024) {
#pragma unroll
        for (int fm = 0; fm < 2; ++fm) {
          floatx4 t4 = {};
          t4 = __builtin_amdgcn_mfma_f32_16x16x32_bf16(rf[2 * fnT],     af[fm][0], t4, 0, 0, 0);
          t4 = __builtin_amdgcn_mfma_f32_16x16x32_bf16(rf[2 * fnT + 1], af[fm][1], t4, 0, 0, 0);
          // lane holds T[i = fm*16+lrow][u = u0+lq*4+r], r=0..3 (consecutive u)
          if (u0 + lq * 4 + 4 <= LDT) {
            uint2 v; v.x = pkbf(t4[0], t4[1]); v.y = pkbf(t4[2], t4[3]);
            *(uint2*)(Tls + (long)(fm * 16 + lrow) * LDT + u0 + lq * 4) = v;
          }
        }
      }
    }
  }

  // K fragment prefetch (issued before the barrier; consumed after)
  bf16x8 kfA[8], kfB[8];
#pragma unroll
  for (int x = 0; x < 8; ++x)
    kfA[x] = *(const bf16x8*)(Kb + (long)(j0w + (x >> 1) * 16 + lrow) * 1536 + (x & 1) * 32 + lq * 8);
#pragma unroll
  for (int x = 0; x < 8; ++x)
    kfB[x] = *(const bf16x8*)(Kb + (long)(j0w + (4 + (x >> 1)) * 16 + lrow) * 1536 + (x & 1) * 32 + lq * 8);
  __syncthreads();   // barrier 1: T visible to all waves

  // ---- phase 1: S = Q K^T (f32 in regs) + bias from T ----
  floatx4 sacc[2][8] = {};
  __builtin_amdgcn_s_setprio(1);
#pragma unroll
  for (int fn = 0; fn < 4; ++fn) {
    sacc[0][fn] = __builtin_amdgcn_mfma_f32_16x16x32_bf16(af[0][0], kfA[2 * fn],     sacc[0][fn], 0, 0, 0);
    sacc[0][fn] = __builtin_amdgcn_mfma_f32_16x16x32_bf16(af[0][1], kfA[2 * fn + 1], sacc[0][fn], 0, 0, 0);
    sacc[1][fn] = __builtin_amdgcn_mfma_f32_16x16x32_bf16(af[1][0], kfA[2 * fn],     sacc[1][fn], 0, 0, 0);
    sacc[1][fn] = __builtin_amdgcn_mfma_f32_16x16x32_bf16(af[1][1], kfA[2 * fn + 1], sacc[1][fn], 0, 0, 0);
  }
#pragma unroll
  for (int fn = 4; fn < 8; ++fn) {
    sacc[0][fn] = __builtin_amdgcn_mfma_f32_16x16x32_bf16(af[0][0], kfB[2 * (fn - 4)],     sacc[0][fn], 0, 0, 0);
    sacc[0][fn] = __builtin_amdgcn_mfma_f32_16x16x32_bf16(af[0][1], kfB[2 * (fn - 4) + 1], sacc[0][fn], 0, 0, 0);
    sacc[1][fn] = __builtin_amdgcn_mfma_f32_16x16x32_bf16(af[1][0], kfB[2 * (fn - 4)],     sacc[1][fn], 0, 0, 0);
    sacc[1][fn] = __builtin_amdgcn_mfma_f32_16x16x32_bf16(af[1][1], kfB[2 * (fn - 4) + 1], sacc[1][fn], 0, 0, 0);
  }
  __builtin_amdgcn_s_setprio(0);

  // rel-pos bias gather from LDS: bias[i][j] = T[i_local][clip(i-j,+-512)+512]
#pragma unroll
  for (int fm = 0; fm < 2; ++fm)
#pragma unroll
    for (int r = 0; r < 4; ++r) {
      const int il = fm * 16 + lq * 4 + r;
      const bf16_t* trow = Tls + il * LDT + 512;
      const int tb = i0 + il - j0w - lrow;
#pragma unroll
      for (int fn = 0; fn < 8; ++fn) {
        int t = tb - fn * 16;
        t = t < -512 ? -512 : (t > 512 ? 512 : t);
        sacc[fm][fn][r] += b2f(trow[t]);
      }
    }

  // ---- phase 2: wave-local softmax (flash rescale deferred to reduce) ----
  float rmax[2][4];
#pragma unroll
  for (int fm = 0; fm < 2; ++fm)
#pragma unroll
    for (int r = 0; r < 4; ++r) {
      float m = sacc[fm][0][r];
#pragma unroll
      for (int fn = 1; fn < 8; ++fn) m = fmaxf(m, sacc[fm][fn][r]);
      rmax[fm][r] = m;
    }
#pragma unroll
  for (int off = 1; off < 16; off <<= 1)   // reduce across the 16 j-lanes (lrow)
#pragma unroll
    for (int fm = 0; fm < 2; ++fm)
#pragma unroll
      for (int r = 0; r < 4; ++r)
        rmax[fm][r] = fmaxf(rmax[fm][r], __shfl_xor(rmax[fm][r], off));
  if (lrow == 0)
#pragma unroll
    for (int fm = 0; fm < 2; ++fm)
#pragma unroll
      for (int r = 0; r < 4; ++r)
        scr[(fm * 16 + lq * 4 + r) * 9 + w] = rmax[fm][r];

  float rsum[2][4];
#pragma unroll
  for (int fm = 0; fm < 2; ++fm)
#pragma unroll
    for (int r = 0; r < 4; ++r) {
      float s = 0.f;
#pragma unroll
      for (int fn = 0; fn < 8; ++fn) {
        float e = __expf(sacc[fm][fn][r] - rmax[fm][r]);
        sacc[fm][fn][r] = e;
        s += e;
      }
      rsum[fm][r] = s;
    }
#pragma unroll
  for (int off = 1; off < 16; off <<= 1)
#pragma unroll
    for (int fm = 0; fm < 2; ++fm)
#pragma unroll
      for (int r = 0; r < 4; ++r)
        rsum[fm][r] += __shfl_xor(rsum[fm][r], off);
  if (lrow == 0)
#pragma unroll
    for (int fm = 0; fm < 2; ++fm)
#pragma unroll
      for (int r = 0; r < 4; ++r)
        scr[288 + (fm * 16 + lq * 4 + r) * 9 + w] = rsum[fm][r];

  // VT prefetch, first half (ks 0,1)
  bf16x8 vfA[8];
#pragma unroll
  for (int x = 0; x < 8; ++x)   // x = ks*4 + fd, ks in {0,1}
    vfA[x] = *(const bf16x8*)(VTb + (long)((x & 3) * 16 + lrow) * 1024 + j0w + (x >> 2) * 32 + lq * 8);

  __syncthreads();   // barrier 2: all T gathers done -> safe to alias P over T

  // ---- phase 3a: unnormalized P -> LDS (XOR swizzle ^((i&7)<<4); wave-local) ----
#pragma unroll
  for (int fm = 0; fm < 2; ++fm)
#pragma unroll
    for (int fn = 0; fn < 8; ++fn)
#pragma unroll
      for (int r = 0; r < 4; ++r) {
        const int i = fm * 16 + lq * 4 + r;
        const int j = j0w + fn * 16 + lrow;
        const unsigned boff = (unsigned)(i * 2048 + j * 2) ^ ((unsigned)(i & 7) << 4);
        *(bf16_t*)((char*)Tls + boff) = f2b(sacc[fm][fn][r]);
      }
  // no barrier needed: each wave reads back only its own slab

  // VT prefetch, second half (ks 2,3)
  bf16x8 vfB[8];
#pragma unroll
  for (int x = 0; x < 8; ++x)   // x = ks*4 + fd, ks in {2,3}
    vfB[x] = *(const bf16x8*)(VTb + (long)((x & 3) * 16 + lrow) * 1024 + j0w + 64 + (x >> 2) * 32 + lq * 8);

  // ---- phase 3b: O partials = P_slab @ V_slab ----
  floatx4 oacc[2][4] = {};
  __builtin_amdgcn_s_setprio(1);
#pragma unroll
  for (int ks = 0; ks < 4; ++ks) {
    const int j = j0w + ks * 32;
    bf16x8 ap[2];
#pragma unroll
    for (int fm = 0; fm < 2; ++fm) {
      const int i = fm * 16 + lrow;
      const unsigned boff = (unsigned)(i * 2048 + (j + lq * 8) * 2) ^ ((unsigned)(i & 7) << 4);
      ap[fm] = *(const bf16x8*)((char*)Tls + boff);
    }
#pragma unroll
    for (int fd = 0; fd < 4; ++fd) {
      bf16x8 bv = (ks < 2) ? vfA[(ks << 2) | fd] : vfB[((ks - 2) << 2) | fd];
      oacc[0][fd] = __builtin_amdgcn_mfma_f32_16x16x32_bf16(ap[0], bv, oacc[0][fd], 0, 0, 0);
      oacc[1][fd] = __builtin_amdgcn_mfma_f32_16x16x32_bf16(ap[1], bv, oacc[1][fd], 0, 0, 0);
    }
  }
  __builtin_amdgcn_s_setprio(0);
  __syncthreads();   // barrier 3: all PV reads of P done -> overwrite with partials

  // partials: per-wave f32 [i][64] at float offset w*2048 (re-aliases LDS)
  {
    float* part = (float*)Tls + w * 2048;
#pragma unroll
    for (int fm = 0; fm < 2; ++fm)
#pragma unroll
      for (int fd = 0; fd < 4; ++fd)
#pragma unroll
        for (int r = 0; r < 4; ++r)
          part[(fm * 16 + lq * 4 + r) * 64 + fd * 16 + lrow] = oacc[fm][fd][r];
  }
  __syncthreads();   // barrier 4

  // K-reduce 8 partials with flash rescale + normalization, write O
  {
    const int i = tid >> 4;
    const int d0 = (tid & 15) * 4;
    float mw[8], sw[8];
#pragma unroll
    for (int ww = 0; ww < 8; ++ww) {
      mw[ww] = scr[i * 9 + ww];
      sw[ww] = scr[288 + i * 9 + ww];
    }
    float M = mw[0];
#pragma unroll
    for (int ww = 1; ww < 8; ++ww) M = fmaxf(M, mw[ww]);
    float fac[8]; float tot = 0.f;
#pragma unroll
    for (int ww = 0; ww < 8; ++ww) { fac[ww] = __expf(mw[ww] - M); tot += sw[ww] * fac[ww]; }
    const float inv = 1.f / tot;
    floatx4 s = {};
#pragma unroll
    for (int ww = 0; ww < 8; ++ww) {
      floatx4 p = *(const floatx4*)((const float*)Tls + ww * 2048 + i * 64 + d0);
      s += p * fac[ww];
    }
    hbf4 o4;
#pragma unroll
    for (int m = 0; m < 4; ++m) o4.h[m] = f2b(s[m] * inv);
    *(hbf4*)(O + (long)(b * 1024 + i0 + i) * 512 + zh * 64 + d0) = o4;
  }
}

// ---------------------------------------------------------------- glue kernels
__global__ __launch_bounds__(256) void diag_kernel(float* __restrict__ out, long n, float v) {
  long i = (long)blockIdx.x * 256 + threadIdx.x;
  if (i < n) out[i] = v;
}

// batched weight prep: 9 transposes (f32->bf16, optional scale / GLU perm) + relpad
struct PrepJobs {
  const float* src[10];
  bf16_t*      dst[10];
  int R[10], C[10], gx[10], start[10];
  float scale[10];
  int   mode[10];   // 0 transpose, 1 transpose+GLU col-interleave, 2 relpad
  int   njobs;
};

__global__ __launch_bounds__(256) void prep_kernel(PrepJobs P) {
  __shared__ float t[32][33];
  const int bid = blockIdx.x;
  int j = 0;
  while (j + 1 < P.njobs && bid >= P.start[j + 1]) ++j;
  const int tile = bid - P.start[j];
  const int tid = threadIdx.x;
  if (P.mode[j] == 2) {   // relpad: [1025,64] f32 -> [1152,64] bf16 (zero tail)
    int i = tile * 256 + tid;
    if (i < 73728) {
      int r = i >> 6, c = i & 63;
      P.dst[j][i] = (r < 1025) ? f2b(P.src[j][r * 64 + c]) : f2b(0.f);
    }
    return;
  }
  const int gx = P.gx[j];
  const int c0 = (tile % gx) * 32, r0 = (tile / gx) * 32;
  const int C = P.C[j], R = P.R[j];
  const float scale = P.scale[j];
  const int tx = tid & 31, ty = tid >> 5;
#pragma unroll
  for (int i = 0; i < 4; ++i)
    t[ty + i * 8][tx] = P.src[j][(long)(r0 + ty + i * 8) * C + c0 + tx];
  __syncthreads();
#pragma unroll
  for (int i = 0; i < 4; ++i) {
    int c = c0 + ty + i * 8;
    int row = (P.mode[j] == 1) ? ((c < 1024) ? 2 * c : 2 * (c - 1024) + 1) : c;
    P.dst[j][(long)row * R + r0 + tx] = f2b(t[tx][ty + i * 8] * scale);
  }
}

template <bool F32OUT>
__global__ __launch_bounds__(256) void ln_kernel(const float* __restrict__ X, const float* __restrict__ gam,
                                                 const float* __restrict__ bet, void* __restrict__ outv) {
  int row = blockIdx.x, tid = threadIdx.x;
  const float* x = X + (long)row * 512;
  float a = x[tid], b = x[tid + 256];
  float s = a + b, q = a * a + b * b;
  for (int off = 32; off; off >>= 1) { s += __shfl_down(s, off); q += __shfl_down(q, off); }
  __shared__ float red[8];
  int w = tid >> 6;
  if ((tid & 63) == 0) { red[w] = s; red[w + 4] = q; }
  __syncthreads();
  float ts = red[0] + red[1] + red[2] + red[3];
  float tq = red[4] + red[5] + red[6] + red[7];
  float mean = ts * (1.f / 512.f);
  float var = tq * (1.f / 512.f) - mean * mean;
  float rs = rsqrtf(var + 1e-5f);
  float o0 = (a - mean) * rs * gam[tid]       + bet[tid];
  float o1 = (b - mean) * rs * gam[tid + 256] + bet[tid + 256];
  if constexpr (F32OUT) {
    float* out = (float*)outv;
    out[(long)row * 512 + tid]       = o0;
    out[(long)row * 512 + tid + 256] = o1;
  } else {
    bf16_t* out = (bf16_t*)outv;
    out[(long)row * 512 + tid]       = f2b(o0);
    out[(long)row * 512 + tid + 256] = f2b(o1);
  }
}

// VT[z=b*8+h][d][j] = QKV[(b*1024+j)*1536 + 1024 + h*64 + d]
__global__ __launch_bounds__(256) void vt_kernel(const bf16_t* __restrict__ QKV, bf16_t* __restrict__ VT) {
  int jb = blockIdx.x, z = blockIdx.y;
  int b = z >> 3, h = z & 7;
  const bf16_t* src = QKV + (long)b * 1024 * 1536 + 1024 + h * 64;
  bf16_t* dst = VT + (long)z * 65536;
  __shared__ bf16_t t[64][65];
  int tid = threadIdx.x;
#pragma unroll
  for (int i = 0; i < 16; ++i) {
    int l = i * 256 + tid;
    int j = l >> 6, d = l & 63;
    t[d][j] = src[(long)(jb * 64 + j) * 1536 + d];
  }
  __syncthreads();
#pragma unroll
  for (int i = 0; i < 16; ++i) {
    int l = i * 256 + tid;
    int d = l >> 6, j = l & 63;
    dst[(long)d * 1024 + jb * 64 + j] = t[d][j];
  }
}

__global__ __launch_bounds__(256) void dwconv_kernel(const bf16_t* __restrict__ G, const float* __restrict__ dw,
    const float* __restrict__ db, const float* __restrict__ bng, const float* __restrict__ bnb,
    const float* __restrict__ bnm, const float* __restrict__ bnv, bf16_t* __restrict__ out) {
  int n0 = blockIdx.x * 32, c0 = blockIdx.y * 64, b = blockIdx.z;
  __shared__ bf16_t t[62][64];
  __shared__ float dws[31][64];
  int tid = threadIdx.x;
  const bf16_t* src = G + (long)b * 1024 * 1024 + c0;
  // vectorized staging: 62 rows x 64 cols = 496 hbf8 chunks
#pragma unroll
  for (int i = 0; i < 2; ++i) {
    int l = i * 256 + tid;
    if (l < 496) {
      int rr = l >> 3, c8 = (l & 7) * 8;
      int n = n0 - 15 + rr;
      hbf8 v;
      if (n >= 0 && n < 1024) v = *(const hbf8*)(src + (long)n * 1024 + c8);
      else { for (int m = 0; m < 8; ++m) v.h[m] = f2b(0.f); }
      *(hbf8*)&t[rr][c8] = v;
    }
  }
#pragma unroll
  for (int i = 0; i < 8; ++i) {
    int l = i * 256 + tid;
    if (l < 1984) {
      int k = l >> 6, c = l & 63;
      dws[k][c] = dw[(long)(c0 + c) * 31 + k];
    }
  }
  __syncthreads();
  int c = tid & 63, nl = tid >> 6;
  float rs = rsqrtf(bnv[c0 + c] + 1e-5f);
  float sc = rs * bng[c0 + c];
  float ab = (db[c0 + c] - bnm[c0 + c]) * sc + bnb[c0 + c];
#pragma unroll
  for (int j = 0; j < 8; ++j) {
    int rr = nl * 8 + j;
    float s = 0.f;
#pragma unroll
    for (int k = 0; k < 31; ++k) s += b2f(t[rr + k][c]) * dws[k][c];
    float y = s * sc + ab;
    out[((long)b * 1024 + n0 + rr) * 1024 + c0 + c] = f2b(y * sig_(y));
  }
}

// ---------------------------------------------------------------- launch
extern "C" void kernel_launch(void* const* d_in, const int* in_sizes, int n_in,
                              void* d_out, int out_size, void* d_ws, size_t ws_size,
                              hipStream_t stream) {
  auto fail = [&](float code) {
    diag_kernel<<<(out_size + 255) / 256, 256, 0, stream>>>((float*)d_out, out_size, code);
  };
  if (n_in != 34)             { fail(70.f);  return; }
  if (in_sizes[0] != 4194304) { fail(80.f);  return; }

  const float* x     = (const float*)d_in[0];
  const float* f1_g  = (const float*)d_in[1];
  const float* f1_b  = (const float*)d_in[2];
  const float* f1_w1 = (const float*)d_in[3];
  const float* f1_b1 = (const float*)d_in[4];
  const float* f1_w2 = (const float*)d_in[5];
  const float* f1_b2 = (const float*)d_in[6];
  const float* a_g   = (const float*)d_in[7];
  const float* a_b   = (const float*)d_in[8];
  const float* wq    = (const float*)d_in[9];
  const float* wkv   = (const float*)d_in[10];
  const float* wo    = (const float*)d_in[11];
  const float* wo_b  = (const float*)d_in[12];
  const float* rel   = (const float*)d_in[13];
  const float* c_g   = (const float*)d_in[14];
  const float* c_b   = (const float*)d_in[15];
  const float* cw1   = (const float*)d_in[16];
  const float* cb1   = (const float*)d_in[17];
  const float* dwp   = (const float*)d_in[18];
  const float* dbp   = (const float*)d_in[19];
  const float* bn_g  = (const float*)d_in[20];
  const float* bn_b  = (const float*)d_in[21];
  const float* bn_m  = (const float*)d_in[22];
  const float* bn_v  = (const float*)d_in[23];
  const float* cw2   = (const float*)d_in[24];
  const float* cb2   = (const float*)d_in[25];
  const float* f2_g  = (const float*)d_in[26];
  const float* f2_b  = (const float*)d_in[27];
  const float* f2_w1 = (const float*)d_in[28];
  const float* f2_b1 = (const float*)d_in[29];
  const float* f2_w2 = (const float*)d_in[30];
  const float* f2_b2 = (const float*)d_in[31];
  const float* p_g   = (const float*)d_in[32];
  const float* p_b   = (const float*)d_in[33];

  // ---- workspace arena ----
  // X 16.78M | WT 13.63M | D 33.55M {QKV 25.2M + VT 8.4M}/{GLU 16.8M + DWO 16.8M}
  // | E: MID 33.55M | RELP 147K
  char* ws = (char*)d_ws;
  const size_t OFF_X  = 0;
  const size_t OFF_WT = 16777216;
  const size_t OFF_D  = 30408704;
  const size_t OFF_E  = 63963136;
  const size_t relp_off = OFF_E + 33554432;
  if (ws_size < relp_off + 147456ULL) { fail(200.f); return; }

  float*  X   = (float*)(ws + OFF_X);
  bf16_t* WT  = (bf16_t*)(ws + OFF_WT);
  bf16_t* QKV = (bf16_t*)(ws + OFF_D);
  bf16_t* VT  = (bf16_t*)(ws + OFF_D + 25165824);
  bf16_t* GLU = (bf16_t*)(ws + OFF_D);
  bf16_t* DWO = (bf16_t*)(ws + OFF_D + 16777216);
  bf16_t* MID = (bf16_t*)(ws + OFF_E);
  bf16_t* RELP= (bf16_t*)(ws + relp_off);
  bf16_t* H   = (bf16_t*)d_out;   // bf16 scratch inside f32 out buffer
  bf16_t* O   = (bf16_t*)d_out;   // final f32 LN overwrites at the end

  bf16_t* f1_w1t = WT;            bf16_t* f1_w2t = WT + 1048576;
  bf16_t* wqkvt  = WT + 2097152;  // [1536][512]: wq rows 0-511 (pre-scaled), wkv rows 512-1535
  bf16_t* wot    = WT + 2883584;  bf16_t* cw1t   = WT + 3145728;  // column-interleaved
  bf16_t* cw2t   = WT + 4194304;  bf16_t* f2_w1t = WT + 4718592;
  bf16_t* f2_w2t = WT + 5767168;

  auto GA = [](const bf16_t* A, const bf16_t* Bt, const float* bias, bf16_t* C,
               float* resid, const float* srcf, int K, int lda, int ldb, int ldc,
               float alpha, float beta) {
    GemmArgs g{}; g.A = A; g.Bt = Bt; g.bias = bias; g.srcf = srcf; g.C = C; g.resid = resid;
    g.K = K; g.lda = lda; g.ldb = ldb; g.ldc = ldc;
    g.sAb = g.sAh = g.sBb = g.sBh = g.sCb = g.sCh = 0; g.alpha = alpha; g.beta = beta;
    return g;
  };

  // ---- batched weight prep (9 transposes + relpad in ONE dispatch) ----
  {
    PrepJobs P{};
    auto set = [&](int idx, const float* s, bf16_t* d, int R, int C, int start,
                   float sc, int mode) {
      P.src[idx] = s; P.dst[idx] = d; P.R[idx] = R; P.C[idx] = C;
      P.gx[idx] = C / 32; P.start[idx] = start; P.scale[idx] = sc; P.mode[idx] = mode;
    };
    //            src     dst              R     C     start  scale   mode
    set(0, f1_w1, f1_w1t,          512, 2048,    0, 1.f,    0);
    set(1, f1_w2, f1_w2t,         2048,  512, 1024, 1.f,    0);
    set(2, wq,    wqkvt,           512,  512, 2048, 0.125f, 0);
    set(3, wkv,   wqkvt + 262144,  512, 1024, 2304, 1.f,    0);
    set(4, wo,    wot,             512,  512, 2816, 1.f,    0);
    set(5, cw1,   cw1t,            512, 2048, 3072, 1.f,    1);
    set(6, cw2,   cw2t,           1024,  512, 4096, 1.f,    0);
    set(7, f2_w1, f2_w1t,          512, 2048, 4608, 1.f,    0);
    set(8, f2_w2, f2_w2t,         2048,  512, 5632, 1.f,    0);
    set(9, rel,   RELP,           1025,   64, 6656, 1.f,    2);
    P.njobs = 10;
    prep_kernel<<<6944, 256, 0, stream>>>(P);
  }

  // ---- FF1 half-step ----  (LN1 reads x directly; EPI2 writes X = x + 0.5*(...))
  ln_kernel<false><<<8192, 256, 0, stream>>>(x, f1_g, f1_b, H);
  { GemmArgs g = GA(H, f1_w1t, f1_b1, MID, nullptr, nullptr, 512, 512, 512, 2048, 1.f, 0.f);
    gemm_bt<128, 128, 2, 2, 1><<<dim3(16, 64, 1), 256, 0, stream>>>(g); }
  { GemmArgs g = GA(MID, f1_w2t, f1_b2, nullptr, X, x, 2048, 2048, 2048, 512, 1.f, 0.5f);
    gemm_bt<64, 128, 1, 4, 2><<<dim3(4, 128, 1), 256, 0, stream>>>(g); }

  // ---- attention ----
  ln_kernel<false><<<8192, 256, 0, stream>>>(X, a_g, a_b, H);
  { GemmArgs g = GA(H, wqkvt, nullptr, QKV, nullptr, nullptr, 512, 512, 512, 1536, 1.f, 0.f);
    gemm_bt<128, 128, 2, 2, 0><<<dim3(12, 64, 1), 256, 0, stream>>>(g); }   // q|k|v (q scale folded)
  vt_kernel<<<dim3(16, 64), 256, 0, stream>>>(QKV, VT);

  // fused: T=q@rel^T (in-LDS), S = qk^T + bias, wave-local softmax, O = P @ V
  attn_kernel<<<dim3(32, 64), 512, 0, stream>>>(QKV, VT, RELP, O);

  { GemmArgs g = GA(O, wot, wo_b, nullptr, X, nullptr, 512, 512, 512, 512, 1.f, 1.f);
    gemm_bt<64, 128, 1, 4, 2><<<dim3(4, 128, 1), 256, 0, stream>>>(g); }   // x += o@wo + b

  // ---- conv module ----
  ln_kernel<false><<<8192, 256, 0, stream>>>(X, c_g, c_b, H);
  { GemmArgs g = GA(H, cw1t, cb1, GLU, nullptr, nullptr, 512, 512, 512, 1024, 1.f, 0.f);
    gemm_bt<128, 128, 2, 2, 4><<<dim3(16, 64, 1), 256, 0, stream>>>(g); }  // pw1 + bias + GLU
  dwconv_kernel<<<dim3(32, 16, 8), 256, 0, stream>>>(GLU, dwp, dbp, bn_g, bn_b, bn_m, bn_v, DWO);
  { GemmArgs g = GA(DWO, cw2t, cb2, nullptr, X, nullptr, 1024, 1024, 1024, 512, 1.f, 1.f);
    gemm_bt<64, 128, 1, 4, 2><<<dim3(4, 128, 1), 256, 0, stream>>>(g); }   // x += h@cw2 + b

  // ---- FF2 half-step + post-LN (f32 out) ----
  ln_kernel<false><<<8192, 256, 0, stream>>>(X, f2_g, f2_b, H);
  { GemmArgs g = GA(H, f2_w1t, f2_b1, MID, nullptr, nullptr, 512, 512, 512, 2048, 1.f, 0.f);
    gemm_bt<128, 128, 2, 2, 1><<<dim3(16, 64, 1), 256, 0, stream>>>(g); }
  { GemmArgs g = GA(MID, f2_w2t, f2_b2, nullptr, X, nullptr, 2048, 2048, 2048, 512, 1.f, 0.5f);
    gemm_bt<64, 128, 1, 4, 2><<<dim3(4, 128, 1), 256, 0, stream>>>(g); }
  ln_kernel<true><<<8192, 256, 0, stream>>>(X, p_g, p_b, (float*)d_out);
}

// Round 11
// 584.928 us; speedup vs baseline: 1.0810x; 1.0443x over previous
//
#include <hip/hip_runtime.h>
#include <hip/hip_bf16.h>
#include <cstdint>

// Conformer block, MI355X gfx950. f32 inputs, f32 output, bf16 MFMA internals.
// B=8 N=1024 D=512 H=8 DH=64 FF=2048 CI=1024 K=31 MPE=512.
// Round 20: EPI2 residual gemms 64x128 -> 64x64 (512 -> 1024 blocks, 2 -> ~5
// blocks/CU: occupancy attack on the lockstep-barrier latency regime);
// ln_kernel vectorized to float2/packed-bf16x2. All R19 pieces retained
// (setprio attn, swapped-T, flash softmax, BK=32 gemm, batched prep).

using bf16_t = __hip_bfloat16;
typedef __bf16 bf16x8 __attribute__((ext_vector_type(8)));
typedef float floatx4 __attribute__((ext_vector_type(4)));

struct alignas(16) hbf8 { bf16_t h[8]; };
struct alignas(8)  hbf4 { bf16_t h[4]; };

__device__ __forceinline__ float  b2f(bf16_t h) { return __bfloat162float(h); }
__device__ __forceinline__ bf16_t f2b(float f)  { return __float2bfloat16(f); }
__device__ __forceinline__ float  sig_(float x) { return 1.f / (1.f + __expf(-x)); }

// pack 2 f32 -> 2 bf16 in one u32 (low 16 = a, high = b); pure C (R4-verified)
__device__ __forceinline__ unsigned pkbf(float a, float b) {
  bf16_t ha = f2b(a), hb = f2b(b);
  unsigned short ua, ub;
  __builtin_memcpy(&ua, &ha, 2);
  __builtin_memcpy(&ub, &hb, 2);
  return (unsigned)ua | ((unsigned)ub << 16);
}

// async global->LDS, 16B/lane; LDS dest must be wave-uniform base + lane*16 (m97 pattern)
__device__ __forceinline__ void async16(const void* g, void* l) {
  __builtin_amdgcn_global_load_lds(
      (const __attribute__((address_space(1))) unsigned int*)(uintptr_t)g,
      (__attribute__((address_space(3))) unsigned int*)(uintptr_t)l, 16, 0, 0);
}

// ---------------------------------------------------------------- GEMM (MFMA)
// C[M,N] = A[M,K] @ Bt[N,K]^T   (bf16 operands, k-contiguous, f32 accum)
// EPI 0: C_bf16 = alpha*acc + bias
// EPI 1: C_bf16 = swish(acc + bias)
// EPI 2: resid_f32 = (srcf ? srcf[i] : resid[i]) + beta*(acc+bias)
// EPI 4: GLU: bias idx (j>>1)+(j&1)*1024; even-j lanes write
//        C[i][j>>1] = v * sig(partner v) (cw1t stored column-interleaved)
struct GemmArgs {
  const bf16_t* A; const bf16_t* Bt; const float* bias; const float* srcf;
  bf16_t* C; float* resid;
  int K, lda, ldb, ldc;
  long sAb, sAh, sBb, sBh, sCb, sCh;
  float alpha, beta;
};

template <int BM, int BN, int WR, int WC, int EPI>
__global__ __launch_bounds__(256) void gemm_bt(GemmArgs g) {
  constexpr int FM = BM / (WR * 16);
  constexpr int FN = BN / (WC * 16);
  constexpr int IA = (BM * 4) / 256;
  constexpr int IB = (BN * 4) / 256;
  __shared__ __align__(16) bf16_t As[BM * 32];
  __shared__ __align__(16) bf16_t Bs[BN * 32];
  const int tid = threadIdx.x;
  const int lane = tid & 63, w = tid >> 6;
  // XCD-chunked bijective remap (nwg % 8 == 0 for all our launches)
  int bx = blockIdx.x, by = blockIdx.y;
  {
    const int gx = gridDim.x;
    const int nwg = gx * gridDim.y;
    if ((nwg & 7) == 0 && gridDim.z == 1) {
      int lin = by * gx + bx;
      int lid = (lin & 7) * (nwg >> 3) + (lin >> 3);
      bx = lid % gx; by = lid / gx;
    }
  }
  const int bm0 = by * BM, bn0 = bx * BN;
  const int zb = blockIdx.z >> 3, zh = blockIdx.z & 7;
  const bf16_t* Ab = g.A + (long)zb * g.sAb + (long)zh * g.sAh;
  const bf16_t* Bb = g.Bt + (long)zb * g.sBb + (long)zh * g.sBh;
  const int wm0 = (w / WC) * (FM * 16);
  const int wn0 = (w % WC) * (FN * 16);
  const int lrow = lane & 15, lq = lane >> 4;

  floatx4 acc[FM][FN] = {};

  for (int k0 = 0; k0 < g.K; k0 += 32) {
#pragma unroll
    for (int i = 0; i < IA; ++i) {
      int c = i * 256 + tid;
      int m = c >> 2, kk = (c & 3) * 8;
      async16(Ab + (long)(bm0 + m) * g.lda + (k0 + kk), (char*)As + c * 16);
    }
#pragma unroll
    for (int i = 0; i < IB; ++i) {
      int c = i * 256 + tid;
      int n = bn0 + (c >> 2), kk = (c & 3) * 8;
      async16(Bb + (long)n * g.ldb + (k0 + kk), (char*)Bs + c * 16);
    }
    __syncthreads();   // drains vmcnt before s_barrier (compiler-inserted)
    bf16x8 af[FM], bfr[FN];
#pragma unroll
    for (int fm = 0; fm < FM; ++fm)
      af[fm] = *(const bf16x8*)(As + (wm0 + fm * 16 + lrow) * 32 + lq * 8);
#pragma unroll
    for (int fn = 0; fn < FN; ++fn)
      bfr[fn] = *(const bf16x8*)(Bs + (wn0 + fn * 16 + lrow) * 32 + lq * 8);
#pragma unroll
    for (int fm = 0; fm < FM; ++fm)
#pragma unroll
      for (int fn = 0; fn < FN; ++fn)
        acc[fm][fn] = __builtin_amdgcn_mfma_f32_16x16x32_bf16(af[fm], bfr[fn], acc[fm][fn], 0, 0, 0);
    __syncthreads();
  }

  const int bi = bm0 + wm0 + lq * 4;    // + fm*16 + r
  const int bj = bn0 + wn0 + lrow;      // + fn*16
  if constexpr (EPI == 2) {
    float* R = g.resid;
    const float* S = g.srcf;
#pragma unroll
    for (int fm = 0; fm < FM; ++fm)
#pragma unroll
      for (int fn = 0; fn < FN; ++fn) {
        int j = bj + fn * 16;
        float bv = g.bias ? g.bias[j] : 0.f;
#pragma unroll
        for (int r = 0; r < 4; ++r) {
          long i = bi + fm * 16 + r;
          float base = S ? S[i * g.ldc + j] : R[i * g.ldc + j];
          R[i * g.ldc + j] = base + g.beta * (acc[fm][fn][r] + bv);
        }
      }
  } else if constexpr (EPI == 4) {
    bf16_t* C = g.C;
#pragma unroll
    for (int fm = 0; fm < FM; ++fm)
#pragma unroll
      for (int fn = 0; fn < FN; ++fn) {
        int j = bj + fn * 16;
        float bv = g.bias[(j >> 1) + (j & 1) * 1024];
#pragma unroll
        for (int r = 0; r < 4; ++r) {
          int i = bi + fm * 16 + r;
          float v = acc[fm][fn][r] + bv;
          float gp = __shfl_xor(v, 1);
          if ((j & 1) == 0)
            C[(long)i * g.ldc + (j >> 1)] = f2b(v * sig_(gp));
        }
      }
  } else {
    bf16_t* C = g.C + (long)zb * g.sCb + (long)zh * g.sCh;
#pragma unroll
    for (int fm = 0; fm < FM; ++fm)
#pragma unroll
      for (int fn = 0; fn < FN; ++fn) {
        int j = bj + fn * 16;
        float bv = g.bias ? g.bias[j] : 0.f;
#pragma unroll
        for (int r = 0; r < 4; ++r) {
          int i = bi + fm * 16 + r;
          float v = acc[fm][fn][r];
          if constexpr (EPI == 0) v = g.alpha * v + bv;
          if constexpr (EPI == 1) { v += bv; v = v * sig_(v); }
          C[(long)i * g.ldc + j] = f2b(v);
        }
      }
  }
}

// ---------------------------------------------------------------- fused attention
// One block = one (z = b*8+h, 32-row i-tile). 512 threads = 8 waves.
// Wave w owns j-slab [w*128, w*128+128).
// Phase 0: T[i][u] via SWAPPED mfma(rel, q): lane holds 4 consecutive u for
//          row i=lane&15 -> packed b64 stores.
// Phase 1: S = Q K^T (regs, K prefetched) + bias gathered from T. [setprio 1]
// Phase 2: wave-local softmax (flash rescale deferred to K-reduce).
// Phase 3: unnormalized P -> LDS (XOR-swizzled, aliases T), PV with VT
//          prefetched [setprio 1], K-split partials rescaled in the reduce.
// QKV: bf16 [(b*1024+n)*1536 + {q:0|k:512|v:1024} + h*64 + d] (q pre-scaled 1/8)
// VT: bf16 [(b*8+h)*65536 + d*1024 + j]
// RELP: bf16 [1152][64] (rows >=1025 zero)
// O: bf16 [(b*1024+i)*512 + h*64 + d]
__global__ __launch_bounds__(512, 4) void attn_kernel(
    const bf16_t* __restrict__ QKV, const bf16_t* __restrict__ VT,
    const bf16_t* __restrict__ RELP, bf16_t* __restrict__ O) {
  constexpr int LDT = 1028;                         // 2056 B row -> 2-bank rotate
  __shared__ __align__(16) bf16_t Tls[32 * LDT];    // 65792 B; aliased: T -> P -> partials
  __shared__ float scr[576];  // [0,288) m_w (stride 9), [288,576) s_w

  const int tid = threadIdx.x;
  const int w = tid >> 6, lane = tid & 63;
  const int lrow = lane & 15, lq = lane >> 4;
  // XCD-chunked remap: 2048 blocks; each XCD gets all 32 i-tiles of 8 z's
  const int lin = blockIdx.y * gridDim.x + blockIdx.x;   // gridDim.x = 32
  const int lid = (lin & 7) * 256 + (lin >> 3);
  const int z = lid >> 5;
  const int i0 = (lid & 31) * 32;
  const int b = z >> 3, zh = z & 7;
  const int j0w = w * 128;

  const bf16_t* Qb  = QKV + ((long)(b * 1024 + i0)) * 1536 + zh * 64;
  const bf16_t* Kb  = QKV + ((long)b * 1024) * 1536 + 512 + zh * 64;
  const bf16_t* VTb = VT + ((long)(b * 8 + zh)) * 65536;

  // Q fragments: af[fm][ks] covers rows fm*16..+15 (lane lrow), k-half ks.
  bf16x8 af[2][2];
#pragma unroll
  for (int fm = 0; fm < 2; ++fm)
#pragma unroll
    for (int ks = 0; ks < 2; ++ks)
      af[fm][ks] = *(const bf16x8*)(Qb + (long)(fm * 16 + lrow) * 1536 + ks * 32 + lq * 8);

  // ---- phase 0: T[i][u] via swapped tiles = mfma(rel, q); packed b64 stores ----
  {
    const int u0w = w * 144;
    bf16x8 rf[18];
#pragma unroll
    for (int fnT = 0; fnT < 9; ++fnT) {
      const int u0 = u0w + fnT * 16;
      if (u0 <= 1024) {
        rf[2 * fnT]     = *(const bf16x8*)(RELP + (long)(u0 + lrow) * 64 + lq * 8);
        rf[2 * fnT + 1] = *(const bf16x8*)(RELP + (long)(u0 + lrow) * 64 + 32 + lq * 8);
      }
    }
#pragma unroll
    for (int fnT = 0; fnT < 9; ++fnT) {
      const int u0 = u0w + fnT * 16;
      if (u0 <= 1024) {
#pragma unroll
        for (int fm = 0; fm < 2; ++fm) {
          floatx4 t4 = {};
          t4 = __builtin_amdgcn_mfma_f32_16x16x32_bf16(rf[2 * fnT],     af[fm][0], t4, 0, 0, 0);
          t4 = __builtin_amdgcn_mfma_f32_16x16x32_bf16(rf[2 * fnT + 1], af[fm][1], t4, 0, 0, 0);
          // lane holds T[i = fm*16+lrow][u = u0+lq*4+r], r=0..3 (consecutive u)
          if (u0 + lq * 4 + 4 <= LDT) {
            uint2 v; v.x = pkbf(t4[0], t4[1]); v.y = pkbf(t4[2], t4[3]);
            *(uint2*)(Tls + (long)(fm * 16 + lrow) * LDT + u0 + lq * 4) = v;
          }
        }
      }
    }
  }

  // K fragment prefetch (issued before the barrier; consumed after)
  bf16x8 kfA[8], kfB[8];
#pragma unroll
  for (int x = 0; x < 8; ++x)
    kfA[x] = *(const bf16x8*)(Kb + (long)(j0w + (x >> 1) * 16 + lrow) * 1536 + (x & 1) * 32 + lq * 8);
#pragma unroll
  for (int x = 0; x < 8; ++x)
    kfB[x] = *(const bf16x8*)(Kb + (long)(j0w + (4 + (x >> 1)) * 16 + lrow) * 1536 + (x & 1) * 32 + lq * 8);
  __syncthreads();   // barrier 1: T visible to all waves

  // ---- phase 1: S = Q K^T (f32 in regs) + bias from T ----
  floatx4 sacc[2][8] = {};
  __builtin_amdgcn_s_setprio(1);
#pragma unroll
  for (int fn = 0; fn < 4; ++fn) {
    sacc[0][fn] = __builtin_amdgcn_mfma_f32_16x16x32_bf16(af[0][0], kfA[2 * fn],     sacc[0][fn], 0, 0, 0);
    sacc[0][fn] = __builtin_amdgcn_mfma_f32_16x16x32_bf16(af[0][1], kfA[2 * fn + 1], sacc[0][fn], 0, 0, 0);
    sacc[1][fn] = __builtin_amdgcn_mfma_f32_16x16x32_bf16(af[1][0], kfA[2 * fn],     sacc[1][fn], 0, 0, 0);
    sacc[1][fn] = __builtin_amdgcn_mfma_f32_16x16x32_bf16(af[1][1], kfA[2 * fn + 1], sacc[1][fn], 0, 0, 0);
  }
#pragma unroll
  for (int fn = 4; fn < 8; ++fn) {
    sacc[0][fn] = __builtin_amdgcn_mfma_f32_16x16x32_bf16(af[0][0], kfB[2 * (fn - 4)],     sacc[0][fn], 0, 0, 0);
    sacc[0][fn] = __builtin_amdgcn_mfma_f32_16x16x32_bf16(af[0][1], kfB[2 * (fn - 4) + 1], sacc[0][fn], 0, 0, 0);
    sacc[1][fn] = __builtin_amdgcn_mfma_f32_16x16x32_bf16(af[1][0], kfB[2 * (fn - 4)],     sacc[1][fn], 0, 0, 0);
    sacc[1][fn] = __builtin_amdgcn_mfma_f32_16x16x32_bf16(af[1][1], kfB[2 * (fn - 4) + 1], sacc[1][fn], 0, 0, 0);
  }
  __builtin_amdgcn_s_setprio(0);

  // rel-pos bias gather from LDS: bias[i][j] = T[i_local][clip(i-j,+-512)+512]
#pragma unroll
  for (int fm = 0; fm < 2; ++fm)
#pragma unroll
    for (int r = 0; r < 4; ++r) {
      const int il = fm * 16 + lq * 4 + r;
      const bf16_t* trow = Tls + il * LDT + 512;
      const int tb = i0 + il - j0w - lrow;
#pragma unroll
      for (int fn = 0; fn < 8; ++fn) {
        int t = tb - fn * 16;
        t = t < -512 ? -512 : (t > 512 ? 512 : t);
        sacc[fm][fn][r] += b2f(trow[t]);
      }
    }

  // ---- phase 2: wave-local softmax (flash rescale deferred to reduce) ----
  float rmax[2][4];
#pragma unroll
  for (int fm = 0; fm < 2; ++fm)
#pragma unroll
    for (int r = 0; r < 4; ++r) {
      float m = sacc[fm][0][r];
#pragma unroll
      for (int fn = 1; fn < 8; ++fn) m = fmaxf(m, sacc[fm][fn][r]);
      rmax[fm][r] = m;
    }
#pragma unroll
  for (int off = 1; off < 16; off <<= 1)   // reduce across the 16 j-lanes (lrow)
#pragma unroll
    for (int fm = 0; fm < 2; ++fm)
#pragma unroll
      for (int r = 0; r < 4; ++r)
        rmax[fm][r] = fmaxf(rmax[fm][r], __shfl_xor(rmax[fm][r], off));
  if (lrow == 0)
#pragma unroll
    for (int fm = 0; fm < 2; ++fm)
#pragma unroll
      for (int r = 0; r < 4; ++r)
        scr[(fm * 16 + lq * 4 + r) * 9 + w] = rmax[fm][r];

  float rsum[2][4];
#pragma unroll
  for (int fm = 0; fm < 2; ++fm)
#pragma unroll
    for (int r = 0; r < 4; ++r) {
      float s = 0.f;
#pragma unroll
      for (int fn = 0; fn < 8; ++fn) {
        float e = __expf(sacc[fm][fn][r] - rmax[fm][r]);
        sacc[fm][fn][r] = e;
        s += e;
      }
      rsum[fm][r] = s;
    }
#pragma unroll
  for (int off = 1; off < 16; off <<= 1)
#pragma unroll
    for (int fm = 0; fm < 2; ++fm)
#pragma unroll
      for (int r = 0; r < 4; ++r)
        rsum[fm][r] += __shfl_xor(rsum[fm][r], off);
  if (lrow == 0)
#pragma unroll
    for (int fm = 0; fm < 2; ++fm)
#pragma unroll
      for (int r = 0; r < 4; ++r)
        scr[288 + (fm * 16 + lq * 4 + r) * 9 + w] = rsum[fm][r];

  // VT prefetch, first half (ks 0,1)
  bf16x8 vfA[8];
#pragma unroll
  for (int x = 0; x < 8; ++x)   // x = ks*4 + fd, ks in {0,1}
    vfA[x] = *(const bf16x8*)(VTb + (long)((x & 3) * 16 + lrow) * 1024 + j0w + (x >> 2) * 32 + lq * 8);

  __syncthreads();   // barrier 2: all T gathers done -> safe to alias P over T

  // ---- phase 3a: unnormalized P -> LDS (XOR swizzle ^((i&7)<<4); wave-local) ----
#pragma unroll
  for (int fm = 0; fm < 2; ++fm)
#pragma unroll
    for (int fn = 0; fn < 8; ++fn)
#pragma unroll
      for (int r = 0; r < 4; ++r) {
        const int i = fm * 16 + lq * 4 + r;
        const int j = j0w + fn * 16 + lrow;
        const unsigned boff = (unsigned)(i * 2048 + j * 2) ^ ((unsigned)(i & 7) << 4);
        *(bf16_t*)((char*)Tls + boff) = f2b(sacc[fm][fn][r]);
      }
  // no barrier needed: each wave reads back only its own slab

  // VT prefetch, second half (ks 2,3)
  bf16x8 vfB[8];
#pragma unroll
  for (int x = 0; x < 8; ++x)   // x = ks*4 + fd, ks in {2,3}
    vfB[x] = *(const bf16x8*)(VTb + (long)((x & 3) * 16 + lrow) * 1024 + j0w + 64 + (x >> 2) * 32 + lq * 8);

  // ---- phase 3b: O partials = P_slab @ V_slab ----
  floatx4 oacc[2][4] = {};
  __builtin_amdgcn_s_setprio(1);
#pragma unroll
  for (int ks = 0; ks < 4; ++ks) {
    const int j = j0w + ks * 32;
    bf16x8 ap[2];
#pragma unroll
    for (int fm = 0; fm < 2; ++fm) {
      const int i = fm * 16 + lrow;
      const unsigned boff = (unsigned)(i * 2048 + (j + lq * 8) * 2) ^ ((unsigned)(i & 7) << 4);
      ap[fm] = *(const bf16x8*)((char*)Tls + boff);
    }
#pragma unroll
    for (int fd = 0; fd < 4; ++fd) {
      bf16x8 bv = (ks < 2) ? vfA[(ks << 2) | fd] : vfB[((ks - 2) << 2) | fd];
      oacc[0][fd] = __builtin_amdgcn_mfma_f32_16x16x32_bf16(ap[0], bv, oacc[0][fd], 0, 0, 0);
      oacc[1][fd] = __builtin_amdgcn_mfma_f32_16x16x32_bf16(ap[1], bv, oacc[1][fd], 0, 0, 0);
    }
  }
  __builtin_amdgcn_s_setprio(0);
  __syncthreads();   // barrier 3: all PV reads of P done -> overwrite with partials

  // partials: per-wave f32 [i][64] at float offset w*2048 (re-aliases LDS)
  {
    float* part = (float*)Tls + w * 2048;
#pragma unroll
    for (int fm = 0; fm < 2; ++fm)
#pragma unroll
      for (int fd = 0; fd < 4; ++fd)
#pragma unroll
        for (int r = 0; r < 4; ++r)
          part[(fm * 16 + lq * 4 + r) * 64 + fd * 16 + lrow] = oacc[fm][fd][r];
  }
  __syncthreads();   // barrier 4

  // K-reduce 8 partials with flash rescale + normalization, write O
  {
    const int i = tid >> 4;
    const int d0 = (tid & 15) * 4;
    float mw[8], sw[8];
#pragma unroll
    for (int ww = 0; ww < 8; ++ww) {
      mw[ww] = scr[i * 9 + ww];
      sw[ww] = scr[288 + i * 9 + ww];
    }
    float M = mw[0];
#pragma unroll
    for (int ww = 1; ww < 8; ++ww) M = fmaxf(M, mw[ww]);
    float fac[8]; float tot = 0.f;
#pragma unroll
    for (int ww = 0; ww < 8; ++ww) { fac[ww] = __expf(mw[ww] - M); tot += sw[ww] * fac[ww]; }
    const float inv = 1.f / tot;
    floatx4 s = {};
#pragma unroll
    for (int ww = 0; ww < 8; ++ww) {
      floatx4 p = *(const floatx4*)((const float*)Tls + ww * 2048 + i * 64 + d0);
      s += p * fac[ww];
    }
    hbf4 o4;
#pragma unroll
    for (int m = 0; m < 4; ++m) o4.h[m] = f2b(s[m] * inv);
    *(hbf4*)(O + (long)(b * 1024 + i0 + i) * 512 + zh * 64 + d0) = o4;
  }
}

// ---------------------------------------------------------------- glue kernels
__global__ __launch_bounds__(256) void diag_kernel(float* __restrict__ out, long n, float v) {
  long i = (long)blockIdx.x * 256 + threadIdx.x;
  if (i < n) out[i] = v;
}

// batched weight prep: 9 transposes (f32->bf16, optional scale / GLU perm) + relpad
struct PrepJobs {
  const float* src[10];
  bf16_t*      dst[10];
  int R[10], C[10], gx[10], start[10];
  float scale[10];
  int   mode[10];   // 0 transpose, 1 transpose+GLU col-interleave, 2 relpad
  int   njobs;
};

__global__ __launch_bounds__(256) void prep_kernel(PrepJobs P) {
  __shared__ float t[32][33];
  const int bid = blockIdx.x;
  int j = 0;
  while (j + 1 < P.njobs && bid >= P.start[j + 1]) ++j;
  const int tile = bid - P.start[j];
  const int tid = threadIdx.x;
  if (P.mode[j] == 2) {   // relpad: [1025,64] f32 -> [1152,64] bf16 (zero tail)
    int i = tile * 256 + tid;
    if (i < 73728) {
      int r = i >> 6, c = i & 63;
      P.dst[j][i] = (r < 1025) ? f2b(P.src[j][r * 64 + c]) : f2b(0.f);
    }
    return;
  }
  const int gx = P.gx[j];
  const int c0 = (tile % gx) * 32, r0 = (tile / gx) * 32;
  const int C = P.C[j], R = P.R[j];
  const float scale = P.scale[j];
  const int tx = tid & 31, ty = tid >> 5;
#pragma unroll
  for (int i = 0; i < 4; ++i)
    t[ty + i * 8][tx] = P.src[j][(long)(r0 + ty + i * 8) * C + c0 + tx];
  __syncthreads();
#pragma unroll
  for (int i = 0; i < 4; ++i) {
    int c = c0 + ty + i * 8;
    int row = (P.mode[j] == 1) ? ((c < 1024) ? 2 * c : 2 * (c - 1024) + 1) : c;
    P.dst[j][(long)row * R + r0 + tx] = f2b(t[tx][ty + i * 8] * scale);
  }
}

template <bool F32OUT>
__global__ __launch_bounds__(256) void ln_kernel(const float* __restrict__ X, const float* __restrict__ gam,
                                                 const float* __restrict__ bet, void* __restrict__ outv) {
  int row = blockIdx.x, tid = threadIdx.x;
  const float* x = X + (long)row * 512;
  float2 v = *(const float2*)(x + tid * 2);
  float a = v.x, b = v.y;
  float s = a + b, q = a * a + b * b;
  for (int off = 32; off; off >>= 1) { s += __shfl_down(s, off); q += __shfl_down(q, off); }
  __shared__ float red[8];
  int w = tid >> 6;
  if ((tid & 63) == 0) { red[w] = s; red[w + 4] = q; }
  __syncthreads();
  float ts = red[0] + red[1] + red[2] + red[3];
  float tq = red[4] + red[5] + red[6] + red[7];
  float mean = ts * (1.f / 512.f);
  float var = tq * (1.f / 512.f) - mean * mean;
  float rs = rsqrtf(var + 1e-5f);
  float2 gm = *(const float2*)(gam + tid * 2);
  float2 bt = *(const float2*)(bet + tid * 2);
  float o0 = (a - mean) * rs * gm.x + bt.x;
  float o1 = (b - mean) * rs * gm.y + bt.y;
  if constexpr (F32OUT) {
    float* out = (float*)outv;
    *(float2*)(out + (long)row * 512 + tid * 2) = make_float2(o0, o1);
  } else {
    unsigned* out = (unsigned*)outv;
    out[(long)row * 256 + tid] = pkbf(o0, o1);
  }
}

// VT[z=b*8+h][d][j] = QKV[(b*1024+j)*1536 + 1024 + h*64 + d]
__global__ __launch_bounds__(256) void vt_kernel(const bf16_t* __restrict__ QKV, bf16_t* __restrict__ VT) {
  int jb = blockIdx.x, z = blockIdx.y;
  int b = z >> 3, h = z & 7;
  const bf16_t* src = QKV + (long)b * 1024 * 1536 + 1024 + h * 64;
  bf16_t* dst = VT + (long)z * 65536;
  __shared__ bf16_t t[64][65];
  int tid = threadIdx.x;
#pragma unroll
  for (int i = 0; i < 16; ++i) {
    int l = i * 256 + tid;
    int j = l >> 6, d = l & 63;
    t[d][j] = src[(long)(jb * 64 + j) * 1536 + d];
  }
  __syncthreads();
#pragma unroll
  for (int i = 0; i < 16; ++i) {
    int l = i * 256 + tid;
    int d = l >> 6, j = l & 63;
    dst[(long)d * 1024 + jb * 64 + j] = t[d][j];
  }
}

__global__ __launch_bounds__(256) void dwconv_kernel(const bf16_t* __restrict__ G, const float* __restrict__ dw,
    const float* __restrict__ db, const float* __restrict__ bng, const float* __restrict__ bnb,
    const float* __restrict__ bnm, const float* __restrict__ bnv, bf16_t* __restrict__ out) {
  int n0 = blockIdx.x * 32, c0 = blockIdx.y * 64, b = blockIdx.z;
  __shared__ bf16_t t[62][64];
  __shared__ float dws[31][64];
  int tid = threadIdx.x;
  const bf16_t* src = G + (long)b * 1024 * 1024 + c0;
  // vectorized staging: 62 rows x 64 cols = 496 hbf8 chunks
#pragma unroll
  for (int i = 0; i < 2; ++i) {
    int l = i * 256 + tid;
    if (l < 496) {
      int rr = l >> 3, c8 = (l & 7) * 8;
      int n = n0 - 15 + rr;
      hbf8 v;
      if (n >= 0 && n < 1024) v = *(const hbf8*)(src + (long)n * 1024 + c8);
      else { for (int m = 0; m < 8; ++m) v.h[m] = f2b(0.f); }
      *(hbf8*)&t[rr][c8] = v;
    }
  }
#pragma unroll
  for (int i = 0; i < 8; ++i) {
    int l = i * 256 + tid;
    if (l < 1984) {
      int k = l >> 6, c = l & 63;
      dws[k][c] = dw[(long)(c0 + c) * 31 + k];
    }
  }
  __syncthreads();
  int c = tid & 63, nl = tid >> 6;
  float rs = rsqrtf(bnv[c0 + c] + 1e-5f);
  float sc = rs * bng[c0 + c];
  float ab = (db[c0 + c] - bnm[c0 + c]) * sc + bnb[c0 + c];
#pragma unroll
  for (int j = 0; j < 8; ++j) {
    int rr = nl * 8 + j;
    float s = 0.f;
#pragma unroll
    for (int k = 0; k < 31; ++k) s += b2f(t[rr + k][c]) * dws[k][c];
    float y = s * sc + ab;
    out[((long)b * 1024 + n0 + rr) * 1024 + c0 + c] = f2b(y * sig_(y));
  }
}

// ---------------------------------------------------------------- launch
extern "C" void kernel_launch(void* const* d_in, const int* in_sizes, int n_in,
                              void* d_out, int out_size, void* d_ws, size_t ws_size,
                              hipStream_t stream) {
  auto fail = [&](float code) {
    diag_kernel<<<(out_size + 255) / 256, 256, 0, stream>>>((float*)d_out, out_size, code);
  };
  if (n_in != 34)             { fail(70.f);  return; }
  if (in_sizes[0] != 4194304) { fail(80.f);  return; }

  const float* x     = (const float*)d_in[0];
  const float* f1_g  = (const float*)d_in[1];
  const float* f1_b  = (const float*)d_in[2];
  const float* f1_w1 = (const float*)d_in[3];
  const float* f1_b1 = (const float*)d_in[4];
  const float* f1_w2 = (const float*)d_in[5];
  const float* f1_b2 = (const float*)d_in[6];
  const float* a_g   = (const float*)d_in[7];
  const float* a_b   = (const float*)d_in[8];
  const float* wq    = (const float*)d_in[9];
  const float* wkv   = (const float*)d_in[10];
  const float* wo    = (const float*)d_in[11];
  const float* wo_b  = (const float*)d_in[12];
  const float* rel   = (const float*)d_in[13];
  const float* c_g   = (const float*)d_in[14];
  const float* c_b   = (const float*)d_in[15];
  const float* cw1   = (const float*)d_in[16];
  const float* cb1   = (const float*)d_in[17];
  const float* dwp   = (const float*)d_in[18];
  const float* dbp   = (const float*)d_in[19];
  const float* bn_g  = (const float*)d_in[20];
  const float* bn_b  = (const float*)d_in[21];
  const float* bn_m  = (const float*)d_in[22];
  const float* bn_v  = (const float*)d_in[23];
  const float* cw2   = (const float*)d_in[24];
  const float* cb2   = (const float*)d_in[25];
  const float* f2_g  = (const float*)d_in[26];
  const float* f2_b  = (const float*)d_in[27];
  const float* f2_w1 = (const float*)d_in[28];
  const float* f2_b1 = (const float*)d_in[29];
  const float* f2_w2 = (const float*)d_in[30];
  const float* f2_b2 = (const float*)d_in[31];
  const float* p_g   = (const float*)d_in[32];
  const float* p_b   = (const float*)d_in[33];

  // ---- workspace arena ----
  // X 16.78M | WT 13.63M | D 33.55M {QKV 25.2M + VT 8.4M}/{GLU 16.8M + DWO 16.8M}
  // | E: MID 33.55M | RELP 147K
  char* ws = (char*)d_ws;
  const size_t OFF_X  = 0;
  const size_t OFF_WT = 16777216;
  const size_t OFF_D  = 30408704;
  const size_t OFF_E  = 63963136;
  const size_t relp_off = OFF_E + 33554432;
  if (ws_size < relp_off + 147456ULL) { fail(200.f); return; }

  float*  X   = (float*)(ws + OFF_X);
  bf16_t* WT  = (bf16_t*)(ws + OFF_WT);
  bf16_t* QKV = (bf16_t*)(ws + OFF_D);
  bf16_t* VT  = (bf16_t*)(ws + OFF_D + 25165824);
  bf16_t* GLU = (bf16_t*)(ws + OFF_D);
  bf16_t* DWO = (bf16_t*)(ws + OFF_D + 16777216);
  bf16_t* MID = (bf16_t*)(ws + OFF_E);
  bf16_t* RELP= (bf16_t*)(ws + relp_off);
  bf16_t* H   = (bf16_t*)d_out;   // bf16 scratch inside f32 out buffer
  bf16_t* O   = (bf16_t*)d_out;   // final f32 LN overwrites at the end

  bf16_t* f1_w1t = WT;            bf16_t* f1_w2t = WT + 1048576;
  bf16_t* wqkvt  = WT + 2097152;  // [1536][512]: wq rows 0-511 (pre-scaled), wkv rows 512-1535
  bf16_t* wot    = WT + 2883584;  bf16_t* cw1t   = WT + 3145728;  // column-interleaved
  bf16_t* cw2t   = WT + 4194304;  bf16_t* f2_w1t = WT + 4718592;
  bf16_t* f2_w2t = WT + 5767168;

  auto GA = [](const bf16_t* A, const bf16_t* Bt, const float* bias, bf16_t* C,
               float* resid, const float* srcf, int K, int lda, int ldb, int ldc,
               float alpha, float beta) {
    GemmArgs g{}; g.A = A; g.Bt = Bt; g.bias = bias; g.srcf = srcf; g.C = C; g.resid = resid;
    g.K = K; g.lda = lda; g.ldb = ldb; g.ldc = ldc;
    g.sAb = g.sAh = g.sBb = g.sBh = g.sCb = g.sCh = 0; g.alpha = alpha; g.beta = beta;
    return g;
  };

  // ---- batched weight prep (9 transposes + relpad in ONE dispatch) ----
  {
    PrepJobs P{};
    auto set = [&](int idx, const float* s, bf16_t* d, int R, int C, int start,
                   float sc, int mode) {
      P.src[idx] = s; P.dst[idx] = d; P.R[idx] = R; P.C[idx] = C;
      P.gx[idx] = C / 32; P.start[idx] = start; P.scale[idx] = sc; P.mode[idx] = mode;
    };
    //            src     dst              R     C     start  scale   mode
    set(0, f1_w1, f1_w1t,          512, 2048,    0, 1.f,    0);
    set(1, f1_w2, f1_w2t,         2048,  512, 1024, 1.f,    0);
    set(2, wq,    wqkvt,           512,  512, 2048, 0.125f, 0);
    set(3, wkv,   wqkvt + 262144,  512, 1024, 2304, 1.f,    0);
    set(4, wo,    wot,             512,  512, 2816, 1.f,    0);
    set(5, cw1,   cw1t,            512, 2048, 3072, 1.f,    1);
    set(6, cw2,   cw2t,           1024,  512, 4096, 1.f,    0);
    set(7, f2_w1, f2_w1t,          512, 2048, 4608, 1.f,    0);
    set(8, f2_w2, f2_w2t,         2048,  512, 5632, 1.f,    0);
    set(9, rel,   RELP,           1025,   64, 6656, 1.f,    2);
    P.njobs = 10;
    prep_kernel<<<6944, 256, 0, stream>>>(P);
  }

  // ---- FF1 half-step ----  (LN1 reads x directly; EPI2 writes X = x + 0.5*(...))
  ln_kernel<false><<<8192, 256, 0, stream>>>(x, f1_g, f1_b, H);
  { GemmArgs g = GA(H, f1_w1t, f1_b1, MID, nullptr, nullptr, 512, 512, 512, 2048, 1.f, 0.f);
    gemm_bt<128, 128, 2, 2, 1><<<dim3(16, 64, 1), 256, 0, stream>>>(g); }
  { GemmArgs g = GA(MID, f1_w2t, f1_b2, nullptr, X, x, 2048, 2048, 2048, 512, 1.f, 0.5f);
    gemm_bt<64, 64, 1, 4, 2><<<dim3(8, 128, 1), 256, 0, stream>>>(g); }

  // ---- attention ----
  ln_kernel<false><<<8192, 256, 0, stream>>>(X, a_g, a_b, H);
  { GemmArgs g = GA(H, wqkvt, nullptr, QKV, nullptr, nullptr, 512, 512, 512, 1536, 1.f, 0.f);
    gemm_bt<128, 128, 2, 2, 0><<<dim3(12, 64, 1), 256, 0, stream>>>(g); }   // q|k|v (q scale folded)
  vt_kernel<<<dim3(16, 64), 256, 0, stream>>>(QKV, VT);

  // fused: T=q@rel^T (in-LDS), S = qk^T + bias, wave-local softmax, O = P @ V
  attn_kernel<<<dim3(32, 64), 512, 0, stream>>>(QKV, VT, RELP, O);

  { GemmArgs g = GA(O, wot, wo_b, nullptr, X, nullptr, 512, 512, 512, 512, 1.f, 1.f);
    gemm_bt<64, 64, 1, 4, 2><<<dim3(8, 128, 1), 256, 0, stream>>>(g); }   // x += o@wo + b

  // ---- conv module ----
  ln_kernel<false><<<8192, 256, 0, stream>>>(X, c_g, c_b, H);
  { GemmArgs g = GA(H, cw1t, cb1, GLU, nullptr, nullptr, 512, 512, 512, 1024, 1.f, 0.f);
    gemm_bt<128, 128, 2, 2, 4><<<dim3(16, 64, 1), 256, 0, stream>>>(g); }  // pw1 + bias + GLU
  dwconv_kernel<<<dim3(32, 16, 8), 256, 0, stream>>>(GLU, dwp, dbp, bn_g, bn_b, bn_m, bn_v, DWO);
  { GemmArgs g = GA(DWO, cw2t, cb2, nullptr, X, nullptr, 1024, 1024, 1024, 512, 1.f, 1.f);
    gemm_bt<64, 64, 1, 4, 2><<<dim3(8, 128, 1), 256, 0, stream>>>(g); }   // x += h@cw2 + b

  // ---- FF2 half-step + post-LN (f32 out) ----
  ln_kernel<false><<<8192, 256, 0, stream>>>(X, f2_g, f2_b, H);
  { GemmArgs g = GA(H, f2_w1t, f2_b1, MID, nullptr, nullptr, 512, 512, 512, 2048, 1.f, 0.f);
    gemm_bt<128, 128, 2, 2, 1><<<dim3(16, 64, 1), 256, 0, stream>>>(g); }
  { GemmArgs g = GA(MID, f2_w2t, f2_b2, nullptr, X, nullptr, 2048, 2048, 2048, 512, 1.f, 0.5f);
    gemm_bt<64, 64, 1, 4, 2><<<dim3(8, 128, 1), 256, 0, stream>>>(g); }
  ln_kernel<true><<<8192, 256, 0, stream>>>(X, p_g, p_b, (float*)d_out);
}